// Round 6
// baseline (652.455 us; speedup 1.0000x reference)
//
#include <hip/hip_runtime.h>
#include <math.h>

#define BB 32
#define NN 1024
#define NEGV (-1e9f)
#define BIGC (1e8f)
#define EPSS 0.1f
#define K2f   14.426950408889634f    // log2(e)/eps
#define TWOK2 28.853900817779268f    // 2*K2f
#define INVK2 0.06931471805599453f   // eps*ln2 = 1/K2f
#define SINK_ITERS 20
#define CHUNKS 16                    // WGs per batch (512-thread WGs, 64 rows each)
#define NBLK (BB * CHUNKS)           // 512 workgroups total
#define BARSTRIDE 32                 // ints per batch: fflags[16] + gflags[16] = 128 B

typedef float f32x2 __attribute__((ext_vector_type(2)));

__device__ __forceinline__ float wave_reduce_sum(float v) {
#pragma unroll
  for (int s = 32; s >= 1; s >>= 1) v += __shfl_xor(v, s, 64);
  return v;
}
__device__ __forceinline__ float wave_reduce_max(float v) {
#pragma unroll
  for (int s = 32; s >= 1; s >>= 1) v = fmaxf(v, __shfl_xor(v, s, 64));
  return v;
}
__device__ __forceinline__ float wave_reduce_min(float v) {
#pragma unroll
  for (int s = 32; s >= 1; s >>= 1) v = fminf(v, __shfl_xor(v, s, 64));
  return v;
}

__device__ __forceinline__ bool getbit(const unsigned* mb, int i) {
  return (mb[i >> 5] >> (i & 31)) & 1u;
}

// Cross-XCD potential exchange: agent-scope RELAXED atomics (sc0/sc1, serviced
// at LLC). No release/acquire => no whole-L2 writeback/invalidate.
__device__ __forceinline__ void pot_st2(float* p, float lo, float hi) {
  const unsigned long long pk =
      ((unsigned long long)__float_as_uint(hi) << 32) | __float_as_uint(lo);
  __hip_atomic_store((unsigned long long*)p, pk, __ATOMIC_RELAXED,
                     __HIP_MEMORY_SCOPE_AGENT);
}
__device__ __forceinline__ void pot_ld2(const float* p, float& lo, float& hi) {
  const unsigned long long pk = __hip_atomic_load(
      (const unsigned long long*)p, __ATOMIC_RELAXED, __HIP_MEMORY_SCOPE_AGENT);
  lo = __uint_as_float((unsigned)pk);
  hi = __uint_as_float((unsigned)(pk >> 32));
}
__device__ __forceinline__ float pot_ld(const float* p) {
  return __hip_atomic_load(p, __ATOMIC_RELAXED, __HIP_MEMORY_SCOPE_AGENT);
}
__device__ __forceinline__ int flag_ld(const int* p) {
  return __hip_atomic_load(p, __ATOMIC_RELAXED, __HIP_MEMORY_SCOPE_AGENT);
}

// Publish own chunk: caller must have passed a __syncthreads() after the pot
// stores (compiler drains vmcnt before s_barrier => stores are at the LLC).
__device__ __forceinline__ void flag_bump(int* fl) {
  __hip_atomic_fetch_add(fl, 1, __ATOMIC_RELAXED, __HIP_MEMORY_SCOPE_AGENT);
}

// Wait until all 16 chunk flags of a side reach gen (one-shot phases only).
__device__ __forceinline__ void wait_all16(const int* flags, int gen, int tid) {
  if (tid < 16) {
    while (flag_ld(&flags[tid]) < gen) __builtin_amdgcn_s_sleep(2);
  }
  __syncthreads();
}

// ---------------------------------------------------------------------------
// Two-pass half-step (exact max) — bit-identical math to legacy sink_step.
// Also captures the (wave-uniform) new potentials into myp[8].
// ---------------------------------------------------------------------------
template<bool CHAMF>
__device__ __forceinline__ void twopass(
    const float4* rl, const float4* cl, const float* Agl, const unsigned* rmb,
    float elab, int c, int wave, int lane, int tid,
    float* __restrict__ potOut, size_t base,
    float invnb, int b, float* __restrict__ cdPart, float* reds, float myp[8])
{
  float cdacc = 0.0f;
#pragma unroll 1
  for (int grp = 0; grp < 2; ++grp) {
    const int row0 = c * 64 + wave * 8 + grp * 4;

    float xs0[4], xs1[4], xs2[4], xw[4];
    bool rmv[4];
#pragma unroll
    for (int r = 0; r < 4; ++r) {
      const float4 xp = rl[row0 + r];
      xs0[r] = TWOK2 * xp.x; xs1[r] = TWOK2 * xp.y; xs2[r] = TWOK2 * xp.z;
      xw[r] = xp.w;
      rmv[r] = getbit(rmb, row0 + r);
    }

    float u[4][16];
#pragma unroll
    for (int j = 0; j < 16; ++j) {
      const int m = lane + j * 64;
      const float4 yp = cl[m];
      const float aj = Agl[m];
#pragma unroll
      for (int r = 0; r < 4; ++r) {
        float t = fmaf(xs0[r], yp.x, aj);
        t = fmaf(xs1[r], yp.y, t);
        t = fmaf(xs2[r], yp.z, t);
        u[r][j] = t;
      }
    }

    float gm[4];
#pragma unroll
    for (int r = 0; r < 4; ++r) {
      const float a0 = fmaxf(fmaxf(u[r][0], u[r][1]), u[r][2]);
      const float a1 = fmaxf(fmaxf(u[r][3], u[r][4]), u[r][5]);
      const float a2 = fmaxf(fmaxf(u[r][6], u[r][7]), u[r][8]);
      const float a3 = fmaxf(fmaxf(u[r][9], u[r][10]), u[r][11]);
      const float a4 = fmaxf(fmaxf(u[r][12], u[r][13]), u[r][14]);
      const float mr = fmaxf(fmaxf(fmaxf(a0, a1), a2),
                             fmaxf(fmaxf(a3, a4), u[r][15]));
      gm[r] = wave_reduce_max(mr);
    }

    float ss[4] = {0.f, 0.f, 0.f, 0.f};
#pragma unroll
    for (int j = 0; j < 16; ++j) {
#pragma unroll
      for (int r = 0; r < 4; ++r)
        ss[r] += __builtin_amdgcn_exp2f(u[r][j] - gm[r]);
    }
#pragma unroll
    for (int r = 0; r < 4; ++r) ss[r] = wave_reduce_sum(ss[r]);

    float pv[4];
#pragma unroll
    for (int r = 0; r < 4; ++r) {
      const float lse2 = gm[r] + __builtin_amdgcn_logf(ss[r]);  // log2 domain
      const float el = rmv[r] ? elab : (EPSS * NEGV);
      pv[r] = el + xw[r] - INVK2 * lse2;
      myp[grp * 4 + r] = pv[r];        // wave-uniform capture
    }
    if (lane == 0) {
      pot_st2(&potOut[base + row0 + 0], pv[0], pv[1]);
      pot_st2(&potOut[base + row0 + 2], pv[2], pv[3]);
      if constexpr (CHAMF) {
#pragma unroll
        for (int r = 0; r < 4; ++r)
          if (rmv[r]) cdacc += fmaxf(fmaf(-INVK2, gm[r], xw[r]), 0.0f);
      }
    }
  }

  if constexpr (CHAMF) {
    if (lane == 0) reds[wave] = cdacc;
    __syncthreads();
    if (tid == 0) {
      float s = 0.f;
#pragma unroll
      for (int w = 0; w < 8; ++w) s += reds[w];
      cdPart[(size_t)b * CHUNKS + c] = s * invnb * (1.0f / BB);
    }
  }
}

// ---------------------------------------------------------------------------
// Streaming one-pass half-step: consumes the opposite potentials CHUNK BY
// CHUNK via per-chunk ready flags (summation term j uses exactly chunk j's
// columns, so ascending-j consumption preserves the bit-exact sum order).
// Per j: wait flags[j] >= gen (usually satisfied), one coalesced dword pot
// load (prefetched one j ahead under the previous j's compute), aj computed
// in registers: aj = mask ? fma(K2, pot, -K2*|y|^2) : -1e30 — identical to
// the old LDS Ag build. No LDS staging, no intra-WG syncs in this phase.
// Packed dual-FP32 row math identical to the verified R4 onepass.
// ---------------------------------------------------------------------------
__device__ __forceinline__ void onepass_stream(
    const float4* rl, const float4* cl, const unsigned* cmb,
    const float* __restrict__ potIn, const int* __restrict__ cflags, int gen,
    float elab, int row0, int lane, float* __restrict__ potOut, size_t base,
    float fp[8], const unsigned* rmb)
{
  // early probe of chunk 0 so the pot load's latency overlaps row setup
  while (flag_ld(&cflags[0]) < gen) __builtin_amdgcn_s_sleep(1);
  float pv = pot_ld(&potIn[base + lane]);

  f32x2 xs0[4], xs1[4], xs2[4], sh2[4], acc2[4];
  bool rmv[8];
#pragma unroll
  for (int p = 0; p < 4; ++p) {
    const float4 xa = rl[row0 + 2 * p];
    const float4 xb = rl[row0 + 2 * p + 1];
    rmv[2 * p]     = getbit(rmb, row0 + 2 * p);
    rmv[2 * p + 1] = getbit(rmb, row0 + 2 * p + 1);
    xs0[p] = f32x2{TWOK2 * xa.x, TWOK2 * xb.x};
    xs1[p] = f32x2{TWOK2 * xa.y, TWOK2 * xb.y};
    xs2[p] = f32x2{TWOK2 * xa.z, TWOK2 * xb.z};
    sh2[p] = f32x2{
        rmv[2 * p]     ? (K2f * (elab + xa.w - fp[2 * p]))     : 3.0e38f,
        rmv[2 * p + 1] ? (K2f * (elab + xb.w - fp[2 * p + 1])) : 3.0e38f};
    acc2[p] = f32x2{0.f, 0.f};
  }

#pragma unroll 4
  for (int j = 0; j < 16; ++j) {
    float pvn = 0.0f;
    if (j < 15) {                      // wave-uniform branch
      while (flag_ld(&cflags[j + 1]) < gen) __builtin_amdgcn_s_sleep(1);
      pvn = pot_ld(&potIn[base + (j + 1) * 64 + lane]);
    }
    const int m = lane + j * 64;
    const float4 q = cl[m];
    const float aj = getbit(cmb, m) ? fmaf(K2f, pv, -K2f * q.w) : -1e30f;
    const f32x2 qx = {q.x, q.x}, qy = {q.y, q.y}, qz = {q.z, q.z};
    const f32x2 aj2 = {aj, aj};
#pragma unroll
    for (int p = 0; p < 4; ++p) {
      f32x2 t = __builtin_elementwise_fma(xs0[p], qx, aj2);
      t = __builtin_elementwise_fma(xs1[p], qy, t);
      t = __builtin_elementwise_fma(xs2[p], qz, t);
      const f32x2 e = t - sh2[p];
      const f32x2 ex = {__builtin_amdgcn_exp2f(e.x), __builtin_amdgcn_exp2f(e.y)};
      acc2[p] += ex;
    }
    pv = pvn;
  }

  float acc[8];
#pragma unroll
  for (int p = 0; p < 4; ++p) { acc[2 * p] = acc2[p].x; acc[2 * p + 1] = acc2[p].y; }
#pragma unroll
  for (int r = 0; r < 8; ++r) acc[r] = wave_reduce_sum(acc[r]);

#pragma unroll
  for (int r = 0; r < 8; ++r) {
    const float l2 = fminf(fmaxf(__builtin_amdgcn_logf(acc[r]), -120.0f), 120.0f);
    fp[r] = rmv[r] ? (fp[r] - INVK2 * l2) : (EPSS * NEGV);
  }
  if (lane == 0) {
#pragma unroll
    for (int r = 0; r < 8; r += 2)
      pot_st2(&potOut[base + row0 + r], fp[r], fp[r + 1]);
  }
}

// ---------------------------------------------------------------------------
// Persistent cooperative kernel: per-chunk dataflow Sinkhorn.
// b = gid&31, c = gid>>5 (R2/R4 mapping — best measured FETCH/occupancy).
// flags: fflags[16] / gflags[16] per batch, monotonic publish counters.
// ---------------------------------------------------------------------------
__global__ __launch_bounds__(512, 4) void fused_sink(
    const float* __restrict__ xset, const int* __restrict__ xm,
    const float* __restrict__ yset, const int* __restrict__ ym,
    float* __restrict__ f, float* __restrict__ g,
    float* __restrict__ cd_part, float* __restrict__ emd_part,
    int* __restrict__ bar)
{
  const int gid = blockIdx.x;
  const int b = gid & (BB - 1), c = gid >> 5;
  const int tid = threadIdx.x, wave = tid >> 6, lane = tid & 63;
  const size_t base = (size_t)b * NN;
  int* fflags = bar + b * BARSTRIDE;
  int* gflags = fflags + 16;

  __shared__ float4 xl[NN];            // 16 KB  points x (x,y,z,|p|^2)
  __shared__ float4 yl[NN];            // 16 KB  points y
  __shared__ float Ag[NN];             //  4 KB  column terms (iter0 / EMD only)
  __shared__ float gvs[NN];            //  4 KB  staging (EMD g / chamfer w)
  __shared__ unsigned xmb[NN / 32], ymb[NN / 32];
  __shared__ float cred[16];
  __shared__ float reds[8];
  __shared__ float sscal[4];           // elax, elay, invx, invy

  // ---- stage points + masks once ----
  float cntx = 0.f, cnty = 0.f;
  for (int i = tid; i < NN; i += 512) {
    const size_t ix = (base + (size_t)i) * 3;
    const float x0 = xset[ix], x1 = xset[ix + 1], x2 = xset[ix + 2];
    const float y0 = yset[ix], y1 = yset[ix + 1], y2 = yset[ix + 2];
    xl[i] = make_float4(x0, x1, x2, x0 * x0 + x1 * x1 + x2 * x2);
    yl[i] = make_float4(y0, y1, y2, y0 * y0 + y1 * y1 + y2 * y2);
    const int mxv = xm[base + i], myv = ym[base + i];
    cntx += mxv ? 1.0f : 0.0f;
    cnty += myv ? 1.0f : 0.0f;
    const unsigned long long bx = __ballot(mxv != 0);
    const unsigned long long by = __ballot(myv != 0);
    if (lane == 0) {
      const int w0 = i >> 5;           // i is 64-aligned for lane 0
      xmb[w0] = (unsigned)bx; xmb[w0 + 1] = (unsigned)(bx >> 32);
      ymb[w0] = (unsigned)by; ymb[w0 + 1] = (unsigned)(by >> 32);
    }
  }
  cntx = wave_reduce_sum(cntx);
  cnty = wave_reduce_sum(cnty);
  if (lane == 0) { cred[wave] = cntx; cred[8 + wave] = cnty; }
  __syncthreads();
  if (tid == 0) {
    float a = 0.f, cc = 0.f;
#pragma unroll
    for (int i = 0; i < 8; ++i) { a += cred[i]; cc += cred[8 + i]; }
    sscal[0] = -EPSS * logf(a);        // elax
    sscal[1] = -EPSS * logf(cc);       // elay
    sscal[2] = 1.0f / a;               // invx
    sscal[3] = 1.0f / cc;              // invy
  }
  __syncthreads();
  const float elax = sscal[0], elay = sscal[1], invx = sscal[2], invy = sscal[3];

  float myf[8], myg[8];
  const int row0w = c * 64 + wave * 8;

  // ---- iter 0: f-step (two-pass, g = 0) + fused chamfer x->y ----
  for (int i = tid; i < NN; i += 512)
    Ag[i] = getbit(ymb, i) ? (-K2f * yl[i].w) : -1e30f;
  __syncthreads();
  twopass<true>(xl, yl, Ag, xmb, elax, c, wave, lane, tid, f, base,
                invx, b, cd_part, reds, myf);
  // pot stores drained by twopass's trailing __syncthreads (CHAMF reduction)
  if (tid == 0) flag_bump(&fflags[c]);                // f chunk published (gen 1)

  // ---- chamfer y->x (independent of sinkhorn state) ----
  for (int i = tid; i < NN; i += 512)
    gvs[i] = getbit(xmb, i) ? xl[i].w : BIGC;   // mask-folded |x|^2
  __syncthreads();
  {
    float acc = 0.0f;
#pragma unroll 1
    for (int rr = 0; rr < 8; ++rr) {
      const int row = c * 64 + wave * 8 + rr;
      const float4 yp = yl[row];
      const float ys0 = -2.f * yp.x, ys1 = -2.f * yp.y, ys2 = -2.f * yp.z;
      float dmin = BIGC;
#pragma unroll
      for (int j = 0; j < 16; ++j) {
        const int m = lane + j * 64;
        const float4 xq = xl[m];
        float d = fmaf(ys0, xq.x, gvs[m]);
        d = fmaf(ys1, xq.y, d);
        d = fmaf(ys2, xq.z, d);
        dmin = fminf(dmin, d);
      }
      dmin = wave_reduce_min(dmin);
      if (lane == 0 && getbit(ymb, row)) acc += fmaxf(yp.w + dmin, 0.0f);
    }
    __syncthreads();                   // protect reds reuse
    if (lane == 0) reds[wave] = acc;
    __syncthreads();
    if (tid == 0) {
      float s = 0.f;
#pragma unroll
      for (int w = 0; w < 8; ++w) s += reds[w];
      cd_part[BB * CHUNKS + (size_t)b * CHUNKS + c] = s * invy * (1.0f / BB);
    }
  }

  // ---- iter 0: g-step (two-pass, pot_in = f; one-shot => wait-all) ----
  wait_all16(fflags, 1, tid);
  {
    const int i2 = tid << 1;
    float f0, f1;
    pot_ld2(&f[base + i2], f0, f1);
    Ag[i2]     = getbit(xmb, i2)     ? fmaf(K2f, f0, -K2f * xl[i2].w)     : -1e30f;
    Ag[i2 + 1] = getbit(xmb, i2 + 1) ? fmaf(K2f, f1, -K2f * xl[i2 + 1].w) : -1e30f;
  }
  __syncthreads();
  twopass<false>(yl, xl, Ag, ymb, elay, c, wave, lane, tid, g, base,
                 0.f, b, nullptr, reds, myg);
  __syncthreads();                     // drain lane-0 g stores
  if (tid == 0) flag_bump(&gflags[c]);                // g chunk published (gen 1)

  // ---- iterations 1..19: streaming one-pass half-steps ----
  for (int it = 1; it < SINK_ITERS; ++it) {
    // f-step: consumes g chunks at gen it, publishes f at gen it+1
    onepass_stream(xl, yl, ymb, g, gflags, it, elax, row0w, lane, f, base,
                   myf, xmb);
    __syncthreads();
    if (tid == 0) flag_bump(&fflags[c]);
    // g-step: consumes f chunks at gen it+1, publishes g at gen it+1
    onepass_stream(yl, xl, xmb, f, fflags, it + 1, elay, row0w, lane, g, base,
                   myg, ymb);
    __syncthreads();
    if (tid == 0) flag_bump(&gflags[c]);
  }

  // ---- EMD plan evaluation (one-shot => wait-all + LDS staging) ----
  wait_all16(gflags, SINK_ITERS, tid);
  {
    const int i2 = tid << 1;
    float g0, g1;
    pot_ld2(&g[base + i2], g0, g1);
    gvs[i2] = g0; gvs[i2 + 1] = g1;
    Ag[i2]     = getbit(ymb, i2)     ? fmaf(K2f, g0, -K2f * yl[i2].w)     : -1e30f;
    Ag[i2 + 1] = getbit(ymb, i2 + 1) ? fmaf(K2f, g1, -K2f * yl[i2 + 1].w) : -1e30f;
  }
  __syncthreads();
  {
    float acc = 0.0f;
#pragma unroll 1
    for (int rr = 0; rr < 8; ++rr) {
      const int row = row0w + rr;
      const float4 xp = xl[row];
      const float fv = myf[rr];        // == stored f (wave-uniform capture)
      const float rc = fmaf(K2f, fv, -K2f * xp.w);
      const float xs0 = TWOK2 * xp.x, xs1 = TWOK2 * xp.y, xs2 = TWOK2 * xp.z;
      const bool rv = getbit(xmb, row);
#pragma unroll
      for (int j = 0; j < 16; ++j) {
        const int m = lane + j * 64;
        const float4 yp = yl[m];
        const float a = rv ? (Ag[m] + rc) : -1e30f;
        float t = fmaf(xs0, yp.x, a);
        t = fmaf(xs1, yp.y, t);
        t = fmaf(xs2, yp.z, t);
        float C = fmaf(t, -INVK2, fv + gvs[m]);
        C = fmaxf(C, 0.0f);
        acc = fmaf(__builtin_amdgcn_exp2f(t), C, acc);
      }
    }
    acc = wave_reduce_sum(acc);
    __syncthreads();
    if (lane == 0) reds[wave] = acc;
    __syncthreads();
    if (tid == 0) {
      float s = 0.f;
#pragma unroll
      for (int w = 0; w < 8; ++w) s += reds[w];
      emd_part[(size_t)b * CHUNKS + c] = s * (1.0f / BB);
    }
  }
}

// ===========================================================================
// Legacy multi-kernel path (fallback if cooperative launch is unavailable).
// ===========================================================================
__global__ __launch_bounds__(1024) void prep_kernel(
    const float* __restrict__ xset, const int* __restrict__ xm,
    const float* __restrict__ yset, const int* __restrict__ ym,
    float4* __restrict__ xpack, float4* __restrict__ ypack,
    float* __restrict__ elax, float* __restrict__ elay,
    float* __restrict__ invx, float* __restrict__ invy)
{
  const int b = blockIdx.x;
  const int n = threadIdx.x;
  const size_t idx = (size_t)b * NN + n;

  const float x0 = xset[idx * 3 + 0], x1 = xset[idx * 3 + 1], x2 = xset[idx * 3 + 2];
  const float y0 = yset[idx * 3 + 0], y1 = yset[idx * 3 + 1], y2 = yset[idx * 3 + 2];
  xpack[idx] = make_float4(x0, x1, x2, x0 * x0 + x1 * x1 + x2 * x2);
  ypack[idx] = make_float4(y0, y1, y2, y0 * y0 + y1 * y1 + y2 * y2);

  float cx = wave_reduce_sum(xm[idx] ? 1.0f : 0.0f);
  float cy = wave_reduce_sum(ym[idx] ? 1.0f : 0.0f);

  __shared__ float sx[16], sy[16];
  const int wave = n >> 6, lane = n & 63;
  if (lane == 0) { sx[wave] = cx; sy[wave] = cy; }
  __syncthreads();
  if (n == 0) {
    float a = 0.0f, c = 0.0f;
#pragma unroll
    for (int i = 0; i < 16; ++i) { a += sx[i]; c += sy[i]; }
    elax[b] = -EPSS * logf(a);
    elay[b] = -EPSS * logf(c);
    invx[b] = 1.0f / a;
    invy[b] = 1.0f / c;
  }
}

template<bool FIRST, bool CHAMF>
__global__ __launch_bounds__(512) void sink_step(
    const float4* __restrict__ rowpk, const float4* __restrict__ redpk,
    const int* __restrict__ rowmask, const int* __restrict__ redmask,
    const float* __restrict__ pot_in, float* __restrict__ pot_out,
    const float* __restrict__ ela,
    const float* __restrict__ invn,
    float* __restrict__ cd_part)
{
  const int b = blockIdx.y, chunk = blockIdx.x, tid = threadIdx.x;
  const int wave = tid >> 6, lane = tid & 63;
  const size_t base = (size_t)b * NN;

  __shared__ float4 ypk[NN];
  __shared__ float Aj[NN];
  __shared__ float reds[8];

  for (int i = tid; i < NN; i += 512) {
    const float4 yp = redpk[base + i];
    ypk[i] = yp;
    float a;
    if constexpr (FIRST)
      a = redmask[base + i] ? (-K2f * yp.w) : -1e30f;
    else
      a = redmask[base + i] ? fmaf(K2f, pot_in[base + i], -K2f * yp.w) : -1e30f;
    Aj[i] = a;
  }
  __syncthreads();

  const float elab = ela[b];
  float cdacc = 0.0f;

#pragma unroll 1
  for (int grp = 0; grp < 2; ++grp) {
    const int row0 = chunk * 64 + wave * 8 + grp * 4;

    float xs0[4], xs1[4], xs2[4], xw[4];
    int rmv[4];
#pragma unroll
    for (int r = 0; r < 4; ++r) {
      const float4 xp = rowpk[base + row0 + r];
      xs0[r] = TWOK2 * xp.x; xs1[r] = TWOK2 * xp.y; xs2[r] = TWOK2 * xp.z;
      xw[r] = xp.w;
      rmv[r] = rowmask[base + row0 + r];
    }

    float u[4][16];
#pragma unroll
    for (int j = 0; j < 16; ++j) {
      const int m = lane + j * 64;
      const float4 yp = ypk[m];
      const float aj = Aj[m];
#pragma unroll
      for (int r = 0; r < 4; ++r) {
        float t = fmaf(xs0[r], yp.x, aj);
        t = fmaf(xs1[r], yp.y, t);
        t = fmaf(xs2[r], yp.z, t);
        u[r][j] = t;
      }
    }

    float gm[4];
#pragma unroll
    for (int r = 0; r < 4; ++r) {
      const float a0 = fmaxf(fmaxf(u[r][0], u[r][1]), u[r][2]);
      const float a1 = fmaxf(fmaxf(u[r][3], u[r][4]), u[r][5]);
      const float a2 = fmaxf(fmaxf(u[r][6], u[r][7]), u[r][8]);
      const float a3 = fmaxf(fmaxf(u[r][9], u[r][10]), u[r][11]);
      const float a4 = fmaxf(fmaxf(u[r][12], u[r][13]), u[r][14]);
      const float mr = fmaxf(fmaxf(fmaxf(a0, a1), a2),
                             fmaxf(fmaxf(a3, a4), u[r][15]));
      gm[r] = wave_reduce_max(mr);
    }

    float ss[4] = {0.f, 0.f, 0.f, 0.f};
#pragma unroll
    for (int j = 0; j < 16; ++j) {
#pragma unroll
      for (int r = 0; r < 4; ++r)
        ss[r] += __builtin_amdgcn_exp2f(u[r][j] - gm[r]);
    }
#pragma unroll
    for (int r = 0; r < 4; ++r) ss[r] = wave_reduce_sum(ss[r]);

    if (lane == 0) {
#pragma unroll
      for (int r = 0; r < 4; ++r) {
        const float lse2 = gm[r] + __builtin_amdgcn_logf(ss[r]);
        const float el = rmv[r] ? elab : (EPSS * NEGV);
        pot_out[base + row0 + r] = el + xw[r] - INVK2 * lse2;
        if constexpr (CHAMF) {
          if (rmv[r])
            cdacc += fmaxf(fmaf(-INVK2, gm[r], xw[r]), 0.0f);
        }
      }
    }
  }

  if constexpr (CHAMF) {
    if (lane == 0) reds[wave] = cdacc;
    __syncthreads();
    if (tid == 0) {
      float s = 0.f;
#pragma unroll
      for (int w = 0; w < 8; ++w) s += reds[w];
      cd_part[(size_t)b * CHUNKS + chunk] = s * invn[b] * (1.0f / BB);
    }
  }
}

__global__ __launch_bounds__(512) void sink_fast(
    const float4* __restrict__ rowpk, const float4* __restrict__ redpk,
    const int* __restrict__ rowmask, const int* __restrict__ redmask,
    const float* __restrict__ pot_in, float* __restrict__ fpot,
    const float* __restrict__ ela)
{
  const int b = blockIdx.y, chunk = blockIdx.x, tid = threadIdx.x;
  const int wave = tid >> 6, lane = tid & 63;
  const size_t base = (size_t)b * NN;

  __shared__ float4 colq[NN];

  for (int i = tid; i < NN; i += 512) {
    const float4 yp = redpk[base + i];
    const float aj = redmask[base + i]
        ? fmaf(K2f, pot_in[base + i], -K2f * yp.w) : -1e30f;
    colq[i] = make_float4(yp.x, yp.y, yp.z, aj);
  }
  __syncthreads();

  const float elab = ela[b];
  const int row0 = chunk * 64 + wave * 8;

  float xs0[8], xs1[8], xs2[8], sh[8], acc[8], fp[8];
  int rmv[8];
#pragma unroll
  for (int r = 0; r < 8; ++r) {
    const float4 xp = rowpk[base + row0 + r];
    rmv[r] = rowmask[base + row0 + r];
    fp[r] = fpot[base + row0 + r];
    xs0[r] = TWOK2 * xp.x; xs1[r] = TWOK2 * xp.y; xs2[r] = TWOK2 * xp.z;
    sh[r] = rmv[r] ? (K2f * (elab + xp.w - fp[r])) : 3.0e38f;
    acc[r] = 0.0f;
  }

#pragma unroll 4
  for (int j = 0; j < 16; ++j) {
    const float4 q = colq[lane + j * 64];
#pragma unroll
    for (int r = 0; r < 8; ++r) {
      float t = fmaf(xs0[r], q.x, q.w);
      t = fmaf(xs1[r], q.y, t);
      t = fmaf(xs2[r], q.z, t);
      acc[r] += __builtin_amdgcn_exp2f(t - sh[r]);
    }
  }

#pragma unroll
  for (int r = 0; r < 8; ++r) acc[r] = wave_reduce_sum(acc[r]);

  if (lane == 0) {
#pragma unroll
    for (int r = 0; r < 8; ++r) {
      const float l2 = fminf(fmaxf(__builtin_amdgcn_logf(acc[r]), -120.0f), 120.0f);
      fpot[base + row0 + r] = rmv[r] ? (fp[r] - INVK2 * l2) : (EPSS * NEGV);
    }
  }
}

__global__ __launch_bounds__(512) void chamfer_dir(
    const float4* __restrict__ rowpk, const float4* __restrict__ redpk,
    const int* __restrict__ rowmask, const int* __restrict__ redmask,
    const float* __restrict__ invn, float* __restrict__ part)
{
  const int b = blockIdx.y, chunk = blockIdx.x, tid = threadIdx.x;
  const int wave = tid >> 6, lane = tid & 63;
  const size_t base = (size_t)b * NN;

  __shared__ float4 xw4[NN];
  for (int i = tid; i < NN; i += 512) {
    float4 xp = redpk[base + i];
    xp.w = redmask[base + i] ? xp.w : BIGC;
    xw4[i] = xp;
  }
  __syncthreads();

  float acc = 0.0f;
#pragma unroll 1
  for (int rr = 0; rr < 8; ++rr) {
    const int row = chunk * 64 + wave * 8 + rr;
    const float4 yp = rowpk[base + row];
    const float ys0 = -2.f * yp.x, ys1 = -2.f * yp.y, ys2 = -2.f * yp.z;
    float dmin = BIGC;
#pragma unroll
    for (int j = 0; j < 16; ++j) {
      const float4 xq = xw4[lane + j * 64];
      float d = fmaf(ys0, xq.x, xq.w);
      d = fmaf(ys1, xq.y, d);
      d = fmaf(ys2, xq.z, d);
      dmin = fminf(dmin, d);
    }
    dmin = wave_reduce_min(dmin);
    if (lane == 0 && rowmask[base + row]) acc += fmaxf(yp.w + dmin, 0.0f);
  }

  __shared__ float reds[8];
  if (lane == 0) reds[wave] = acc;
  __syncthreads();
  if (tid == 0) {
    float s = 0.f;
#pragma unroll
    for (int w = 0; w < 8; ++w) s += reds[w];
    part[(size_t)b * CHUNKS + chunk] = s * invn[b] * (1.0f / BB);
  }
}

__global__ __launch_bounds__(512) void emd_kernel(
    const float4* __restrict__ rowpk, const float4* __restrict__ redpk,
    const int* __restrict__ rowmask, const int* __restrict__ redmask,
    const float* __restrict__ frow, const float* __restrict__ gred,
    float* __restrict__ part)
{
  const int b = blockIdx.y, chunk = blockIdx.x, tid = threadIdx.x;
  const int wave = tid >> 6, lane = tid & 63;
  const size_t base = (size_t)b * NN;

  __shared__ float4 ypk[NN];
  __shared__ float Ag[NN];
  __shared__ float gv[NN];
  for (int i = tid; i < NN; i += 512) {
    const float4 yp = redpk[base + i];
    ypk[i] = yp;
    const float gg = gred[base + i];
    gv[i] = gg;
    Ag[i] = redmask[base + i] ? fmaf(K2f, gg, -K2f * yp.w) : -1e30f;
  }
  __syncthreads();

  float acc = 0.0f;
#pragma unroll 1
  for (int rr = 0; rr < 8; ++rr) {
    const int row = chunk * 64 + wave * 8 + rr;
    const float4 xp = rowpk[base + row];
    const float fv = frow[base + row];
    const float rc = fmaf(K2f, fv, -K2f * xp.w);
    const float xs0 = TWOK2 * xp.x, xs1 = TWOK2 * xp.y, xs2 = TWOK2 * xp.z;
    const bool rv = rowmask[base + row] != 0;
#pragma unroll
    for (int j = 0; j < 16; ++j) {
      const int m = lane + j * 64;
      const float4 yp = ypk[m];
      const float a = rv ? (Ag[m] + rc) : -1e30f;
      float t = fmaf(xs0, yp.x, a);
      t = fmaf(xs1, yp.y, t);
      t = fmaf(xs2, yp.z, t);
      float C = fmaf(t, -INVK2, fv + gv[m]);
      C = fmaxf(C, 0.0f);
      acc = fmaf(__builtin_amdgcn_exp2f(t), C, acc);
    }
  }

  acc = wave_reduce_sum(acc);
  __shared__ float reds[8];
  if (lane == 0) reds[wave] = acc;
  __syncthreads();
  if (tid == 0) {
    float s = 0.f;
#pragma unroll
    for (int w = 0; w < 8; ++w) s += reds[w];
    part[(size_t)b * CHUNKS + chunk] = s * (1.0f / BB);
  }
}

__global__ __launch_bounds__(256) void final_kernel(
    const float* __restrict__ cd_part, const float* __restrict__ emd_part,
    const float* __restrict__ kls, float* __restrict__ out)
{
  const int tid = threadIdx.x, wave = tid >> 6, lane = tid & 63;
  __shared__ float sh[12];
  float s1 = 0.f, s2 = 0.f, s3 = 0.f;
  for (int i = tid; i < 2 * BB * CHUNKS; i += 256) s1 += cd_part[i];
  for (int i = tid; i < BB * CHUNKS; i += 256) s2 += emd_part[i];
  for (int i = tid; i < BB * 5; i += 256) s3 += kls[i];
  s1 = wave_reduce_sum(s1); s2 = wave_reduce_sum(s2); s3 = wave_reduce_sum(s3);
  if (lane == 0) { sh[wave] = s1; sh[4 + wave] = s2; sh[8 + wave] = s3; }
  __syncthreads();
  if (tid == 0) {
    const float cd = sh[0] + sh[1] + sh[2] + sh[3];
    const float emd = sh[4] + sh[5] + sh[6] + sh[7];
    const float kl = (sh[8] + sh[9] + sh[10] + sh[11]) / (float)BB;
    out[0] = 0.01f * kl + (cd + emd);
    out[1] = kl;
    out[2] = cd + emd;
  }
  if (tid < 5) {
    float cs = 0.f;
    for (int b2 = 0; b2 < BB; ++b2) cs += kls[b2 * 5 + tid];
    const float zs[5] = {2.f, 4.f, 8.f, 16.f, 32.f};
    out[3 + tid] = (cs / (float)BB) / (zs[tid] * 16.f);
  }
}

// ---------------------------------------------------------------------------
extern "C" void kernel_launch(void* const* d_in, const int* in_sizes, int n_in,
                              void* d_out, int out_size, void* d_ws, size_t ws_size,
                              hipStream_t stream)
{
  const float* xset = (const float*)d_in[0];
  const int*   xm   = (const int*)d_in[1];
  const float* yset = (const float*)d_in[2];
  const int*   ym   = (const int*)d_in[3];
  const float* kls  = (const float*)d_in[4];

  float* ws = (float*)d_ws;
  float*  f    = ws;                         // 32768
  float*  g    = f + BB * NN;                // 32768
  float*  cd   = g + BB * NN;                // 2*BB*CHUNKS = 1024
  float*  emdp = cd + 2 * BB * CHUNKS;       // BB*CHUNKS = 512
  float*  elax = emdp + BB * CHUNKS;         // BB (legacy path)
  float*  elay = elax + BB;
  float*  invx = elay + BB;
  float*  invy = invx + BB;
  int*    bar  = (int*)(invy + BB);          // BB*BARSTRIDE ints (flags, padded)
  float4* xp4  = (float4*)(ws + 68256);      // legacy path, after bar region
  float4* yp4  = xp4 + BB * NN;

  // chunk flags must start at 0 each launch
  hipMemsetAsync(bar, 0, BB * BARSTRIDE * sizeof(int), stream);

  void* args[] = {(void*)&xset, (void*)&xm, (void*)&yset, (void*)&ym,
                  (void*)&f, (void*)&g, (void*)&cd, (void*)&emdp, (void*)&bar};
  hipError_t cerr = hipLaunchCooperativeKernel(
      reinterpret_cast<void*>(fused_sink), dim3(NBLK), dim3(512), args, 0, stream);

  if (cerr != hipSuccess) {
    // fallback: verified legacy multi-kernel path
    prep_kernel<<<dim3(BB), 1024, 0, stream>>>(xset, xm, yset, ym,
                                               xp4, yp4, elax, elay, invx, invy);
    const dim3 sg(CHUNKS, BB);
    sink_step<true, true><<<sg, 512, 0, stream>>>(xp4, yp4, xm, ym, nullptr, f,
                                                  elax, invx, cd);
    chamfer_dir<<<sg, 512, 0, stream>>>(yp4, xp4, ym, xm, invy, cd + BB * CHUNKS);
    sink_step<false, false><<<sg, 512, 0, stream>>>(yp4, xp4, ym, xm, f, g,
                                                    elay, nullptr, nullptr);
    for (int it = 1; it < SINK_ITERS; ++it) {
      sink_fast<<<sg, 512, 0, stream>>>(xp4, yp4, xm, ym, g, f, elax);
      sink_fast<<<sg, 512, 0, stream>>>(yp4, xp4, ym, xm, f, g, elay);
    }
    emd_kernel<<<sg, 512, 0, stream>>>(xp4, yp4, xm, ym, f, g, emdp);
  }

  final_kernel<<<1, 256, 0, stream>>>(cd, emdp, kls, (float*)d_out);
}

// Round 7
// 644.157 us; speedup vs baseline: 1.0129x; 1.0129x over previous
//
#include <hip/hip_runtime.h>
#include <math.h>

#define BB 32
#define NN 1024
#define NEGV (-1e9f)
#define BIGC (1e8f)
#define EPSS 0.1f
#define K2f   14.426950408889634f    // log2(e)/eps
#define TWOK2 28.853900817779268f    // 2*K2f
#define INVK2 0.06931471805599453f   // eps*ln2 = 1/K2f
#define SINK_ITERS 20
#define CHUNKS 16                    // WGs per batch (512-thread WGs, 64 rows each)
#define NBLK (BB * CHUNKS)           // 512 workgroups total
#define BARSTRIDE 64                 // ints per batch: fflag @0, gflag @32 (2 lines)
#define ARRV (8 * CHUNKS)            // arrivals per generation (8 waves x 16 WGs)

typedef float f32x2 __attribute__((ext_vector_type(2)));

__device__ __forceinline__ float wave_reduce_sum(float v) {
#pragma unroll
  for (int s = 32; s >= 1; s >>= 1) v += __shfl_xor(v, s, 64);
  return v;
}
__device__ __forceinline__ float wave_reduce_max(float v) {
#pragma unroll
  for (int s = 32; s >= 1; s >>= 1) v = fmaxf(v, __shfl_xor(v, s, 64));
  return v;
}
__device__ __forceinline__ float wave_reduce_min(float v) {
#pragma unroll
  for (int s = 32; s >= 1; s >>= 1) v = fminf(v, __shfl_xor(v, s, 64));
  return v;
}

__device__ __forceinline__ bool getbit(const unsigned* mb, int i) {
  return (mb[i >> 5] >> (i & 31)) & 1u;
}

// Cross-XCD potential exchange: agent-scope RELAXED atomics (sc0/sc1, serviced
// at LLC). No release/acquire => no whole-L2 writeback/invalidate.
__device__ __forceinline__ void pot_st2(float* p, float lo, float hi) {
  const unsigned long long pk =
      ((unsigned long long)__float_as_uint(hi) << 32) | __float_as_uint(lo);
  __hip_atomic_store((unsigned long long*)p, pk, __ATOMIC_RELAXED,
                     __HIP_MEMORY_SCOPE_AGENT);
}
__device__ __forceinline__ void pot_ld2(const float* p, float& lo, float& hi) {
  const unsigned long long pk = __hip_atomic_load(
      (const unsigned long long*)p, __ATOMIC_RELAXED, __HIP_MEMORY_SCOPE_AGENT);
  lo = __uint_as_float((unsigned)pk);
  hi = __uint_as_float((unsigned)(pk >> 32));
}
__device__ __forceinline__ float pot_ld(const float* p) {
  return __hip_atomic_load(p, __ATOMIC_RELAXED, __HIP_MEMORY_SCOPE_AGENT);
}

// Wave-level arrive: drain this wave's stores (vmcnt(0) => sc1 stores at LLC),
// then ONE lane issues a fire-and-forget add. No WG convergence on the arrive
// path — the slowest WAVE gates consumers, not the slowest WG barrier.
__device__ __forceinline__ void wave_publish(int* fl, int lane) {
  asm volatile("s_waitcnt vmcnt(0)" ::: "memory");
  if (lane == 0)
    __hip_atomic_fetch_add(fl, 1, __ATOMIC_RELAXED, __HIP_MEMORY_SCOPE_AGENT);
}

// WG-level wait: exactly ONE lane polls (R6 lesson: uniform-address per-lane
// atomics serialize into N transactions — never spin with all lanes), then
// __syncthreads broadcasts. Also orders: all waves of this WG have passed
// their publish (hence finished reading shared LDS) before any rebuild.
__device__ __forceinline__ void wg_wait(const int* fl, int gen, int tid) {
  if (tid == 0) {
    const int target = ARRV * gen;
    while (__hip_atomic_load(fl, __ATOMIC_RELAXED, __HIP_MEMORY_SCOPE_AGENT) < target)
      __builtin_amdgcn_s_sleep(1);
  }
  __syncthreads();
}

// ---------------------------------------------------------------------------
// Two-pass half-step (exact max) — bit-identical math to legacy sink_step.
// Captures the wave-uniform new potentials into myp[8].
// ---------------------------------------------------------------------------
template<bool CHAMF>
__device__ __forceinline__ void twopass(
    const float4* rl, const float4* cl, const float* Agl, const unsigned* rmb,
    float elab, int c, int wave, int lane, int tid,
    float* __restrict__ potOut, size_t base,
    float invnb, int b, float* __restrict__ cdPart, float* reds, float myp[8])
{
  float cdacc = 0.0f;
#pragma unroll 1
  for (int grp = 0; grp < 2; ++grp) {
    const int row0 = c * 64 + wave * 8 + grp * 4;

    float xs0[4], xs1[4], xs2[4], xw[4];
    bool rmv[4];
#pragma unroll
    for (int r = 0; r < 4; ++r) {
      const float4 xp = rl[row0 + r];
      xs0[r] = TWOK2 * xp.x; xs1[r] = TWOK2 * xp.y; xs2[r] = TWOK2 * xp.z;
      xw[r] = xp.w;
      rmv[r] = getbit(rmb, row0 + r);
    }

    float u[4][16];
#pragma unroll
    for (int j = 0; j < 16; ++j) {
      const int m = lane + j * 64;
      const float4 yp = cl[m];
      const float aj = Agl[m];
#pragma unroll
      for (int r = 0; r < 4; ++r) {
        float t = fmaf(xs0[r], yp.x, aj);
        t = fmaf(xs1[r], yp.y, t);
        t = fmaf(xs2[r], yp.z, t);
        u[r][j] = t;
      }
    }

    float gm[4];
#pragma unroll
    for (int r = 0; r < 4; ++r) {
      const float a0 = fmaxf(fmaxf(u[r][0], u[r][1]), u[r][2]);
      const float a1 = fmaxf(fmaxf(u[r][3], u[r][4]), u[r][5]);
      const float a2 = fmaxf(fmaxf(u[r][6], u[r][7]), u[r][8]);
      const float a3 = fmaxf(fmaxf(u[r][9], u[r][10]), u[r][11]);
      const float a4 = fmaxf(fmaxf(u[r][12], u[r][13]), u[r][14]);
      const float mr = fmaxf(fmaxf(fmaxf(a0, a1), a2),
                             fmaxf(fmaxf(a3, a4), u[r][15]));
      gm[r] = wave_reduce_max(mr);
    }

    float ss[4] = {0.f, 0.f, 0.f, 0.f};
#pragma unroll
    for (int j = 0; j < 16; ++j) {
#pragma unroll
      for (int r = 0; r < 4; ++r)
        ss[r] += __builtin_amdgcn_exp2f(u[r][j] - gm[r]);
    }
#pragma unroll
    for (int r = 0; r < 4; ++r) ss[r] = wave_reduce_sum(ss[r]);

    float pv[4];
#pragma unroll
    for (int r = 0; r < 4; ++r) {
      const float lse2 = gm[r] + __builtin_amdgcn_logf(ss[r]);  // log2 domain
      const float el = rmv[r] ? elab : (EPSS * NEGV);
      pv[r] = el + xw[r] - INVK2 * lse2;
      myp[grp * 4 + r] = pv[r];        // wave-uniform capture
    }
    if (lane == 0) {
      pot_st2(&potOut[base + row0 + 0], pv[0], pv[1]);
      pot_st2(&potOut[base + row0 + 2], pv[2], pv[3]);
      if constexpr (CHAMF) {
#pragma unroll
        for (int r = 0; r < 4; ++r)
          if (rmv[r]) cdacc += fmaxf(fmaf(-INVK2, gm[r], xw[r]), 0.0f);
      }
    }
  }

  if constexpr (CHAMF) {
    if (lane == 0) reds[wave] = cdacc;
    __syncthreads();
    if (tid == 0) {
      float s = 0.f;
#pragma unroll
      for (int w = 0; w < 8; ++w) s += reds[w];
      cdPart[(size_t)b * CHUNKS + c] = s * invnb * (1.0f / BB);
    }
  }
}

// ---------------------------------------------------------------------------
// One-pass half-step — packed dual-FP32 (v_pk_*), bit-identical per-row math.
// Own-row potentials carried in registers fp[8] (wave-uniform).
// ---------------------------------------------------------------------------
__device__ __forceinline__ void onepass(
    const float4* rl, const float4* cl, const float* Agl, const unsigned* rmb,
    float elab, int row0, int lane, float* __restrict__ pot, size_t base,
    float fp[8])
{
  f32x2 xs0[4], xs1[4], xs2[4], sh2[4], acc2[4];
  bool rmv[8];
#pragma unroll
  for (int p = 0; p < 4; ++p) {
    const float4 xa = rl[row0 + 2 * p];
    const float4 xb = rl[row0 + 2 * p + 1];
    rmv[2 * p]     = getbit(rmb, row0 + 2 * p);
    rmv[2 * p + 1] = getbit(rmb, row0 + 2 * p + 1);
    xs0[p] = f32x2{TWOK2 * xa.x, TWOK2 * xb.x};
    xs1[p] = f32x2{TWOK2 * xa.y, TWOK2 * xb.y};
    xs2[p] = f32x2{TWOK2 * xa.z, TWOK2 * xb.z};
    sh2[p] = f32x2{
        rmv[2 * p]     ? (K2f * (elab + xa.w - fp[2 * p]))     : 3.0e38f,
        rmv[2 * p + 1] ? (K2f * (elab + xb.w - fp[2 * p + 1])) : 3.0e38f};
    acc2[p] = f32x2{0.f, 0.f};
  }

#pragma unroll 4
  for (int j = 0; j < 16; ++j) {
    const int m = lane + j * 64;
    const float4 q = cl[m];
    const float aj = Agl[m];
    const f32x2 qx = {q.x, q.x}, qy = {q.y, q.y}, qz = {q.z, q.z};
    const f32x2 aj2 = {aj, aj};
#pragma unroll
    for (int p = 0; p < 4; ++p) {
      f32x2 t = __builtin_elementwise_fma(xs0[p], qx, aj2);
      t = __builtin_elementwise_fma(xs1[p], qy, t);
      t = __builtin_elementwise_fma(xs2[p], qz, t);
      const f32x2 e = t - sh2[p];
      const f32x2 ex = {__builtin_amdgcn_exp2f(e.x), __builtin_amdgcn_exp2f(e.y)};
      acc2[p] += ex;
    }
  }

  float acc[8];
#pragma unroll
  for (int p = 0; p < 4; ++p) { acc[2 * p] = acc2[p].x; acc[2 * p + 1] = acc2[p].y; }
#pragma unroll
  for (int r = 0; r < 8; ++r) acc[r] = wave_reduce_sum(acc[r]);

#pragma unroll
  for (int r = 0; r < 8; ++r) {
    const float l2 = fminf(fmaxf(__builtin_amdgcn_logf(acc[r]), -120.0f), 120.0f);
    fp[r] = rmv[r] ? (fp[r] - INVK2 * l2) : (EPSS * NEGV);
  }
  if (lane == 0) {
#pragma unroll
    for (int r = 0; r < 8; r += 2)
      pot_st2(&pot[base + row0 + r], fp[r], fp[r + 1]);
  }
}

// ---------------------------------------------------------------------------
// Persistent cooperative kernel (R4 skeleton + wave-level publish barrier).
// b = gid&31, c = gid>>5 (best measured FETCH/occupancy mapping).
// ---------------------------------------------------------------------------
__global__ __launch_bounds__(512, 4) void fused_sink(
    const float* __restrict__ xset, const int* __restrict__ xm,
    const float* __restrict__ yset, const int* __restrict__ ym,
    float* __restrict__ f, float* __restrict__ g,
    float* __restrict__ cd_part, float* __restrict__ emd_part,
    int* __restrict__ bar)
{
  const int gid = blockIdx.x;
  const int b = gid & (BB - 1), c = gid >> 5;
  const int tid = threadIdx.x, wave = tid >> 6, lane = tid & 63;
  const size_t base = (size_t)b * NN;
  int* fflag = bar + b * BARSTRIDE;        // own 128 B line
  int* gflag = fflag + 32;                 // separate 128 B line

  __shared__ float4 xl[NN];            // 16 KB  points x (x,y,z,|p|^2)
  __shared__ float4 yl[NN];            // 16 KB  points y
  __shared__ float Ag[NN];             //  4 KB  prefolded column terms
  __shared__ float gvs[NN];            //  4 KB  staging (EMD g / chamfer w)
  __shared__ unsigned xmb[NN / 32], ymb[NN / 32];
  __shared__ float cred[16];
  __shared__ float reds[8];
  __shared__ float sscal[4];           // elax, elay, invx, invy

  // ---- stage points + masks once ----
  float cntx = 0.f, cnty = 0.f;
  for (int i = tid; i < NN; i += 512) {
    const size_t ix = (base + (size_t)i) * 3;
    const float x0 = xset[ix], x1 = xset[ix + 1], x2 = xset[ix + 2];
    const float y0 = yset[ix], y1 = yset[ix + 1], y2 = yset[ix + 2];
    xl[i] = make_float4(x0, x1, x2, x0 * x0 + x1 * x1 + x2 * x2);
    yl[i] = make_float4(y0, y1, y2, y0 * y0 + y1 * y1 + y2 * y2);
    const int mxv = xm[base + i], myv = ym[base + i];
    cntx += mxv ? 1.0f : 0.0f;
    cnty += myv ? 1.0f : 0.0f;
    const unsigned long long bx = __ballot(mxv != 0);
    const unsigned long long by = __ballot(myv != 0);
    if (lane == 0) {
      const int w0 = i >> 5;           // i is 64-aligned for lane 0
      xmb[w0] = (unsigned)bx; xmb[w0 + 1] = (unsigned)(bx >> 32);
      ymb[w0] = (unsigned)by; ymb[w0 + 1] = (unsigned)(by >> 32);
    }
  }
  cntx = wave_reduce_sum(cntx);
  cnty = wave_reduce_sum(cnty);
  if (lane == 0) { cred[wave] = cntx; cred[8 + wave] = cnty; }
  __syncthreads();
  if (tid == 0) {
    float a = 0.f, cc = 0.f;
#pragma unroll
    for (int i = 0; i < 8; ++i) { a += cred[i]; cc += cred[8 + i]; }
    sscal[0] = -EPSS * logf(a);        // elax
    sscal[1] = -EPSS * logf(cc);       // elay
    sscal[2] = 1.0f / a;               // invx
    sscal[3] = 1.0f / cc;              // invy
  }
  __syncthreads();
  const float elax = sscal[0], elay = sscal[1], invx = sscal[2], invy = sscal[3];

  float myf[8], myg[8];
  const int row0w = c * 64 + wave * 8;

  // ---- iter 0: f-step (two-pass, g = 0) + fused chamfer x->y ----
  for (int i = tid; i < NN; i += 512)
    Ag[i] = getbit(ymb, i) ? (-K2f * yl[i].w) : -1e30f;
  __syncthreads();
  twopass<true>(xl, yl, Ag, xmb, elax, c, wave, lane, tid, f, base,
                invx, b, cd_part, reds, myf);
  wave_publish(fflag, lane);           // f gen 1 — published BEFORE chamfer so
                                       // the whole chamfer overlaps the wait
  // ---- chamfer y->x (independent of sinkhorn state) ----
  for (int i = tid; i < NN; i += 512)
    gvs[i] = getbit(xmb, i) ? xl[i].w : BIGC;   // mask-folded |x|^2
  __syncthreads();
  {
    float acc = 0.0f;
#pragma unroll 1
    for (int rr = 0; rr < 8; ++rr) {
      const int row = c * 64 + wave * 8 + rr;
      const float4 yp = yl[row];
      const float ys0 = -2.f * yp.x, ys1 = -2.f * yp.y, ys2 = -2.f * yp.z;
      float dmin = BIGC;
#pragma unroll
      for (int j = 0; j < 16; ++j) {
        const int m = lane + j * 64;
        const float4 xq = xl[m];
        float d = fmaf(ys0, xq.x, gvs[m]);
        d = fmaf(ys1, xq.y, d);
        d = fmaf(ys2, xq.z, d);
        dmin = fminf(dmin, d);
      }
      dmin = wave_reduce_min(dmin);
      if (lane == 0 && getbit(ymb, row)) acc += fmaxf(yp.w + dmin, 0.0f);
    }
    __syncthreads();                   // protect reds reuse
    if (lane == 0) reds[wave] = acc;
    __syncthreads();
    if (tid == 0) {
      float s = 0.f;
#pragma unroll
      for (int w = 0; w < 8; ++w) s += reds[w];
      cd_part[BB * CHUNKS + (size_t)b * CHUNKS + c] = s * invy * (1.0f / BB);
    }
  }

  // ---- iter 0: g-step (two-pass, pot_in = f) ----
  wg_wait(fflag, 1, tid);              // usually free (chamfer covered it)
  {
    const int i2 = tid << 1;
    float f0, f1;
    pot_ld2(&f[base + i2], f0, f1);
    Ag[i2]     = getbit(xmb, i2)     ? fmaf(K2f, f0, -K2f * xl[i2].w)     : -1e30f;
    Ag[i2 + 1] = getbit(xmb, i2 + 1) ? fmaf(K2f, f1, -K2f * xl[i2 + 1].w) : -1e30f;
  }
  __syncthreads();
  twopass<false>(yl, xl, Ag, ymb, elay, c, wave, lane, tid, g, base,
                 0.f, b, nullptr, reds, myg);
  wave_publish(gflag, lane);           // g gen 1

  // ---- iterations 1..19: one-pass half-steps ----
  for (int it = 1; it < SINK_ITERS; ++it) {
    // f-step: consumes g gen it, publishes f gen it+1
    wg_wait(gflag, it, tid);
    {
      const int i2 = tid << 1;
      float g0, g1;
      pot_ld2(&g[base + i2], g0, g1);
      Ag[i2]     = getbit(ymb, i2)     ? fmaf(K2f, g0, -K2f * yl[i2].w)     : -1e30f;
      Ag[i2 + 1] = getbit(ymb, i2 + 1) ? fmaf(K2f, g1, -K2f * yl[i2 + 1].w) : -1e30f;
    }
    __syncthreads();
    onepass(xl, yl, Ag, xmb, elax, row0w, lane, f, base, myf);
    wave_publish(fflag, lane);

    // g-step: consumes f gen it+1, publishes g gen it+1
    wg_wait(fflag, it + 1, tid);
    {
      const int i2 = tid << 1;
      float f0, f1;
      pot_ld2(&f[base + i2], f0, f1);
      Ag[i2]     = getbit(xmb, i2)     ? fmaf(K2f, f0, -K2f * xl[i2].w)     : -1e30f;
      Ag[i2 + 1] = getbit(xmb, i2 + 1) ? fmaf(K2f, f1, -K2f * xl[i2 + 1].w) : -1e30f;
    }
    __syncthreads();
    onepass(yl, xl, Ag, ymb, elay, row0w, lane, g, base, myg);
    wave_publish(gflag, lane);
  }

  // ---- EMD plan evaluation (consumes g gen 20) ----
  wg_wait(gflag, SINK_ITERS, tid);
  {
    const int i2 = tid << 1;
    float g0, g1;
    pot_ld2(&g[base + i2], g0, g1);
    gvs[i2] = g0; gvs[i2 + 1] = g1;
    Ag[i2]     = getbit(ymb, i2)     ? fmaf(K2f, g0, -K2f * yl[i2].w)     : -1e30f;
    Ag[i2 + 1] = getbit(ymb, i2 + 1) ? fmaf(K2f, g1, -K2f * yl[i2 + 1].w) : -1e30f;
  }
  __syncthreads();
  {
    float acc = 0.0f;
#pragma unroll 1
    for (int rr = 0; rr < 8; ++rr) {
      const int row = row0w + rr;
      const float4 xp = xl[row];
      const float fv = myf[rr];        // == stored f (wave-uniform capture)
      const float rc = fmaf(K2f, fv, -K2f * xp.w);
      const float xs0 = TWOK2 * xp.x, xs1 = TWOK2 * xp.y, xs2 = TWOK2 * xp.z;
      const bool rv = getbit(xmb, row);
#pragma unroll
      for (int j = 0; j < 16; ++j) {
        const int m = lane + j * 64;
        const float4 yp = yl[m];
        const float a = rv ? (Ag[m] + rc) : -1e30f;
        float t = fmaf(xs0, yp.x, a);
        t = fmaf(xs1, yp.y, t);
        t = fmaf(xs2, yp.z, t);
        float C = fmaf(t, -INVK2, fv + gvs[m]);
        C = fmaxf(C, 0.0f);
        acc = fmaf(__builtin_amdgcn_exp2f(t), C, acc);
      }
    }
    acc = wave_reduce_sum(acc);
    __syncthreads();
    if (lane == 0) reds[wave] = acc;
    __syncthreads();
    if (tid == 0) {
      float s = 0.f;
#pragma unroll
      for (int w = 0; w < 8; ++w) s += reds[w];
      emd_part[(size_t)b * CHUNKS + c] = s * (1.0f / BB);
    }
  }
}

// ===========================================================================
// Legacy multi-kernel path (fallback if cooperative launch is unavailable).
// ===========================================================================
__global__ __launch_bounds__(1024) void prep_kernel(
    const float* __restrict__ xset, const int* __restrict__ xm,
    const float* __restrict__ yset, const int* __restrict__ ym,
    float4* __restrict__ xpack, float4* __restrict__ ypack,
    float* __restrict__ elax, float* __restrict__ elay,
    float* __restrict__ invx, float* __restrict__ invy)
{
  const int b = blockIdx.x;
  const int n = threadIdx.x;
  const size_t idx = (size_t)b * NN + n;

  const float x0 = xset[idx * 3 + 0], x1 = xset[idx * 3 + 1], x2 = xset[idx * 3 + 2];
  const float y0 = yset[idx * 3 + 0], y1 = yset[idx * 3 + 1], y2 = yset[idx * 3 + 2];
  xpack[idx] = make_float4(x0, x1, x2, x0 * x0 + x1 * x1 + x2 * x2);
  ypack[idx] = make_float4(y0, y1, y2, y0 * y0 + y1 * y1 + y2 * y2);

  float cx = wave_reduce_sum(xm[idx] ? 1.0f : 0.0f);
  float cy = wave_reduce_sum(ym[idx] ? 1.0f : 0.0f);

  __shared__ float sx[16], sy[16];
  const int wave = n >> 6, lane = n & 63;
  if (lane == 0) { sx[wave] = cx; sy[wave] = cy; }
  __syncthreads();
  if (n == 0) {
    float a = 0.0f, c = 0.0f;
#pragma unroll
    for (int i = 0; i < 16; ++i) { a += sx[i]; c += sy[i]; }
    elax[b] = -EPSS * logf(a);
    elay[b] = -EPSS * logf(c);
    invx[b] = 1.0f / a;
    invy[b] = 1.0f / c;
  }
}

template<bool FIRST, bool CHAMF>
__global__ __launch_bounds__(512) void sink_step(
    const float4* __restrict__ rowpk, const float4* __restrict__ redpk,
    const int* __restrict__ rowmask, const int* __restrict__ redmask,
    const float* __restrict__ pot_in, float* __restrict__ pot_out,
    const float* __restrict__ ela,
    const float* __restrict__ invn,
    float* __restrict__ cd_part)
{
  const int b = blockIdx.y, chunk = blockIdx.x, tid = threadIdx.x;
  const int wave = tid >> 6, lane = tid & 63;
  const size_t base = (size_t)b * NN;

  __shared__ float4 ypk[NN];
  __shared__ float Aj[NN];
  __shared__ float reds[8];

  for (int i = tid; i < NN; i += 512) {
    const float4 yp = redpk[base + i];
    ypk[i] = yp;
    float a;
    if constexpr (FIRST)
      a = redmask[base + i] ? (-K2f * yp.w) : -1e30f;
    else
      a = redmask[base + i] ? fmaf(K2f, pot_in[base + i], -K2f * yp.w) : -1e30f;
    Aj[i] = a;
  }
  __syncthreads();

  const float elab = ela[b];
  float cdacc = 0.0f;

#pragma unroll 1
  for (int grp = 0; grp < 2; ++grp) {
    const int row0 = chunk * 64 + wave * 8 + grp * 4;

    float xs0[4], xs1[4], xs2[4], xw[4];
    int rmv[4];
#pragma unroll
    for (int r = 0; r < 4; ++r) {
      const float4 xp = rowpk[base + row0 + r];
      xs0[r] = TWOK2 * xp.x; xs1[r] = TWOK2 * xp.y; xs2[r] = TWOK2 * xp.z;
      xw[r] = xp.w;
      rmv[r] = rowmask[base + row0 + r];
    }

    float u[4][16];
#pragma unroll
    for (int j = 0; j < 16; ++j) {
      const int m = lane + j * 64;
      const float4 yp = ypk[m];
      const float aj = Aj[m];
#pragma unroll
      for (int r = 0; r < 4; ++r) {
        float t = fmaf(xs0[r], yp.x, aj);
        t = fmaf(xs1[r], yp.y, t);
        t = fmaf(xs2[r], yp.z, t);
        u[r][j] = t;
      }
    }

    float gm[4];
#pragma unroll
    for (int r = 0; r < 4; ++r) {
      const float a0 = fmaxf(fmaxf(u[r][0], u[r][1]), u[r][2]);
      const float a1 = fmaxf(fmaxf(u[r][3], u[r][4]), u[r][5]);
      const float a2 = fmaxf(fmaxf(u[r][6], u[r][7]), u[r][8]);
      const float a3 = fmaxf(fmaxf(u[r][9], u[r][10]), u[r][11]);
      const float a4 = fmaxf(fmaxf(u[r][12], u[r][13]), u[r][14]);
      const float mr = fmaxf(fmaxf(fmaxf(a0, a1), a2),
                             fmaxf(fmaxf(a3, a4), u[r][15]));
      gm[r] = wave_reduce_max(mr);
    }

    float ss[4] = {0.f, 0.f, 0.f, 0.f};
#pragma unroll
    for (int j = 0; j < 16; ++j) {
#pragma unroll
      for (int r = 0; r < 4; ++r)
        ss[r] += __builtin_amdgcn_exp2f(u[r][j] - gm[r]);
    }
#pragma unroll
    for (int r = 0; r < 4; ++r) ss[r] = wave_reduce_sum(ss[r]);

    if (lane == 0) {
#pragma unroll
      for (int r = 0; r < 4; ++r) {
        const float lse2 = gm[r] + __builtin_amdgcn_logf(ss[r]);
        const float el = rmv[r] ? elab : (EPSS * NEGV);
        pot_out[base + row0 + r] = el + xw[r] - INVK2 * lse2;
        if constexpr (CHAMF) {
          if (rmv[r])
            cdacc += fmaxf(fmaf(-INVK2, gm[r], xw[r]), 0.0f);
        }
      }
    }
  }

  if constexpr (CHAMF) {
    if (lane == 0) reds[wave] = cdacc;
    __syncthreads();
    if (tid == 0) {
      float s = 0.f;
#pragma unroll
      for (int w = 0; w < 8; ++w) s += reds[w];
      cd_part[(size_t)b * CHUNKS + chunk] = s * invn[b] * (1.0f / BB);
    }
  }
}

__global__ __launch_bounds__(512) void sink_fast(
    const float4* __restrict__ rowpk, const float4* __restrict__ redpk,
    const int* __restrict__ rowmask, const int* __restrict__ redmask,
    const float* __restrict__ pot_in, float* __restrict__ fpot,
    const float* __restrict__ ela)
{
  const int b = blockIdx.y, chunk = blockIdx.x, tid = threadIdx.x;
  const int wave = tid >> 6, lane = tid & 63;
  const size_t base = (size_t)b * NN;

  __shared__ float4 colq[NN];

  for (int i = tid; i < NN; i += 512) {
    const float4 yp = redpk[base + i];
    const float aj = redmask[base + i]
        ? fmaf(K2f, pot_in[base + i], -K2f * yp.w) : -1e30f;
    colq[i] = make_float4(yp.x, yp.y, yp.z, aj);
  }
  __syncthreads();

  const float elab = ela[b];
  const int row0 = chunk * 64 + wave * 8;

  float xs0[8], xs1[8], xs2[8], sh[8], acc[8], fp[8];
  int rmv[8];
#pragma unroll
  for (int r = 0; r < 8; ++r) {
    const float4 xp = rowpk[base + row0 + r];
    rmv[r] = rowmask[base + row0 + r];
    fp[r] = fpot[base + row0 + r];
    xs0[r] = TWOK2 * xp.x; xs1[r] = TWOK2 * xp.y; xs2[r] = TWOK2 * xp.z;
    sh[r] = rmv[r] ? (K2f * (elab + xp.w - fp[r])) : 3.0e38f;
    acc[r] = 0.0f;
  }

#pragma unroll 4
  for (int j = 0; j < 16; ++j) {
    const float4 q = colq[lane + j * 64];
#pragma unroll
    for (int r = 0; r < 8; ++r) {
      float t = fmaf(xs0[r], q.x, q.w);
      t = fmaf(xs1[r], q.y, t);
      t = fmaf(xs2[r], q.z, t);
      acc[r] += __builtin_amdgcn_exp2f(t - sh[r]);
    }
  }

#pragma unroll
  for (int r = 0; r < 8; ++r) acc[r] = wave_reduce_sum(acc[r]);

  if (lane == 0) {
#pragma unroll
    for (int r = 0; r < 8; ++r) {
      const float l2 = fminf(fmaxf(__builtin_amdgcn_logf(acc[r]), -120.0f), 120.0f);
      fpot[base + row0 + r] = rmv[r] ? (fp[r] - INVK2 * l2) : (EPSS * NEGV);
    }
  }
}

__global__ __launch_bounds__(512) void chamfer_dir(
    const float4* __restrict__ rowpk, const float4* __restrict__ redpk,
    const int* __restrict__ rowmask, const int* __restrict__ redmask,
    const float* __restrict__ invn, float* __restrict__ part)
{
  const int b = blockIdx.y, chunk = blockIdx.x, tid = threadIdx.x;
  const int wave = tid >> 6, lane = tid & 63;
  const size_t base = (size_t)b * NN;

  __shared__ float4 xw4[NN];
  for (int i = tid; i < NN; i += 512) {
    float4 xp = redpk[base + i];
    xp.w = redmask[base + i] ? xp.w : BIGC;
    xw4[i] = xp;
  }
  __syncthreads();

  float acc = 0.0f;
#pragma unroll 1
  for (int rr = 0; rr < 8; ++rr) {
    const int row = chunk * 64 + wave * 8 + rr;
    const float4 yp = rowpk[base + row];
    const float ys0 = -2.f * yp.x, ys1 = -2.f * yp.y, ys2 = -2.f * yp.z;
    float dmin = BIGC;
#pragma unroll
    for (int j = 0; j < 16; ++j) {
      const float4 xq = xw4[lane + j * 64];
      float d = fmaf(ys0, xq.x, xq.w);
      d = fmaf(ys1, xq.y, d);
      d = fmaf(ys2, xq.z, d);
      dmin = fminf(dmin, d);
    }
    dmin = wave_reduce_min(dmin);
    if (lane == 0 && rowmask[base + row]) acc += fmaxf(yp.w + dmin, 0.0f);
  }

  __shared__ float reds[8];
  if (lane == 0) reds[wave] = acc;
  __syncthreads();
  if (tid == 0) {
    float s = 0.f;
#pragma unroll
    for (int w = 0; w < 8; ++w) s += reds[w];
    part[(size_t)b * CHUNKS + chunk] = s * invn[b] * (1.0f / BB);
  }
}

__global__ __launch_bounds__(512) void emd_kernel(
    const float4* __restrict__ rowpk, const float4* __restrict__ redpk,
    const int* __restrict__ rowmask, const int* __restrict__ redmask,
    const float* __restrict__ frow, const float* __restrict__ gred,
    float* __restrict__ part)
{
  const int b = blockIdx.y, chunk = blockIdx.x, tid = threadIdx.x;
  const int wave = tid >> 6, lane = tid & 63;
  const size_t base = (size_t)b * NN;

  __shared__ float4 ypk[NN];
  __shared__ float Ag[NN];
  __shared__ float gv[NN];
  for (int i = tid; i < NN; i += 512) {
    const float4 yp = redpk[base + i];
    ypk[i] = yp;
    const float gg = gred[base + i];
    gv[i] = gg;
    Ag[i] = redmask[base + i] ? fmaf(K2f, gg, -K2f * yp.w) : -1e30f;
  }
  __syncthreads();

  float acc = 0.0f;
#pragma unroll 1
  for (int rr = 0; rr < 8; ++rr) {
    const int row = chunk * 64 + wave * 8 + rr;
    const float4 xp = rowpk[base + row];
    const float fv = frow[base + row];
    const float rc = fmaf(K2f, fv, -K2f * xp.w);
    const float xs0 = TWOK2 * xp.x, xs1 = TWOK2 * xp.y, xs2 = TWOK2 * xp.z;
    const bool rv = rowmask[base + row] != 0;
#pragma unroll
    for (int j = 0; j < 16; ++j) {
      const int m = lane + j * 64;
      const float4 yp = ypk[m];
      const float a = rv ? (Ag[m] + rc) : -1e30f;
      float t = fmaf(xs0, yp.x, a);
      t = fmaf(xs1, yp.y, t);
      t = fmaf(xs2, yp.z, t);
      float C = fmaf(t, -INVK2, fv + gv[m]);
      C = fmaxf(C, 0.0f);
      acc = fmaf(__builtin_amdgcn_exp2f(t), C, acc);
    }
  }

  acc = wave_reduce_sum(acc);
  __shared__ float reds[8];
  if (lane == 0) reds[wave] = acc;
  __syncthreads();
  if (tid == 0) {
    float s = 0.f;
#pragma unroll
    for (int w = 0; w < 8; ++w) s += reds[w];
    part[(size_t)b * CHUNKS + chunk] = s * (1.0f / BB);
  }
}

__global__ __launch_bounds__(256) void final_kernel(
    const float* __restrict__ cd_part, const float* __restrict__ emd_part,
    const float* __restrict__ kls, float* __restrict__ out)
{
  const int tid = threadIdx.x, wave = tid >> 6, lane = tid & 63;
  __shared__ float sh[12];
  float s1 = 0.f, s2 = 0.f, s3 = 0.f;
  for (int i = tid; i < 2 * BB * CHUNKS; i += 256) s1 += cd_part[i];
  for (int i = tid; i < BB * CHUNKS; i += 256) s2 += emd_part[i];
  for (int i = tid; i < BB * 5; i += 256) s3 += kls[i];
  s1 = wave_reduce_sum(s1); s2 = wave_reduce_sum(s2); s3 = wave_reduce_sum(s3);
  if (lane == 0) { sh[wave] = s1; sh[4 + wave] = s2; sh[8 + wave] = s3; }
  __syncthreads();
  if (tid == 0) {
    const float cd = sh[0] + sh[1] + sh[2] + sh[3];
    const float emd = sh[4] + sh[5] + sh[6] + sh[7];
    const float kl = (sh[8] + sh[9] + sh[10] + sh[11]) / (float)BB;
    out[0] = 0.01f * kl + (cd + emd);
    out[1] = kl;
    out[2] = cd + emd;
  }
  if (tid < 5) {
    float cs = 0.f;
    for (int b2 = 0; b2 < BB; ++b2) cs += kls[b2 * 5 + tid];
    const float zs[5] = {2.f, 4.f, 8.f, 16.f, 32.f};
    out[3 + tid] = (cs / (float)BB) / (zs[tid] * 16.f);
  }
}

// ---------------------------------------------------------------------------
extern "C" void kernel_launch(void* const* d_in, const int* in_sizes, int n_in,
                              void* d_out, int out_size, void* d_ws, size_t ws_size,
                              hipStream_t stream)
{
  const float* xset = (const float*)d_in[0];
  const int*   xm   = (const int*)d_in[1];
  const float* yset = (const float*)d_in[2];
  const int*   ym   = (const int*)d_in[3];
  const float* kls  = (const float*)d_in[4];

  float* ws = (float*)d_ws;
  float*  f    = ws;                         // 32768
  float*  g    = f + BB * NN;                // 32768
  float*  cd   = g + BB * NN;                // 2*BB*CHUNKS = 1024
  float*  emdp = cd + 2 * BB * CHUNKS;       // BB*CHUNKS = 512
  float*  elax = emdp + BB * CHUNKS;         // BB (legacy path)
  float*  elay = elax + BB;
  float*  invx = elay + BB;
  float*  invy = invx + BB;
  int*    bar  = (int*)(invy + BB);          // BB*BARSTRIDE ints (2 lines/batch)
  float4* xp4  = (float4*)(ws + 69248);      // legacy path, after bar region
  float4* yp4  = xp4 + BB * NN;

  // flag counters must start at 0 each launch
  hipMemsetAsync(bar, 0, BB * BARSTRIDE * sizeof(int), stream);

  void* args[] = {(void*)&xset, (void*)&xm, (void*)&yset, (void*)&ym,
                  (void*)&f, (void*)&g, (void*)&cd, (void*)&emdp, (void*)&bar};
  hipError_t cerr = hipLaunchCooperativeKernel(
      reinterpret_cast<void*>(fused_sink), dim3(NBLK), dim3(512), args, 0, stream);

  if (cerr != hipSuccess) {
    // fallback: verified legacy multi-kernel path
    prep_kernel<<<dim3(BB), 1024, 0, stream>>>(xset, xm, yset, ym,
                                               xp4, yp4, elax, elay, invx, invy);
    const dim3 sg(CHUNKS, BB);
    sink_step<true, true><<<sg, 512, 0, stream>>>(xp4, yp4, xm, ym, nullptr, f,
                                                  elax, invx, cd);
    chamfer_dir<<<sg, 512, 0, stream>>>(yp4, xp4, ym, xm, invy, cd + BB * CHUNKS);
    sink_step<false, false><<<sg, 512, 0, stream>>>(yp4, xp4, ym, xm, f, g,
                                                    elay, nullptr, nullptr);
    for (int it = 1; it < SINK_ITERS; ++it) {
      sink_fast<<<sg, 512, 0, stream>>>(xp4, yp4, xm, ym, g, f, elax);
      sink_fast<<<sg, 512, 0, stream>>>(yp4, xp4, ym, xm, f, g, elay);
    }
    emd_kernel<<<sg, 512, 0, stream>>>(xp4, yp4, xm, ym, f, g, emdp);
  }

  final_kernel<<<1, 256, 0, stream>>>(cd, emdp, kls, (float*)d_out);
}

// Round 8
// 380.854 us; speedup vs baseline: 1.7131x; 1.6913x over previous
//
#include <hip/hip_runtime.h>
#include <math.h>

#define BB 32
#define NN 1024
#define NEGV (-1e9f)
#define BIGC (1e8f)
#define EPSS 0.1f
#define K2f   14.426950408889634f    // log2(e)/eps
#define TWOK2 28.853900817779268f    // 2*K2f
#define INVK2 0.06931471805599453f   // eps*ln2 = 1/K2f
#define SINK_ITERS 20
#define CHUNKS 16                    // WGs per batch (512-thread WGs, 64 rows each)
#define NBLK (BB * CHUNKS)           // 512 workgroups total
#define BARSTRIDE 32                 // ints per batch counter (128 B line padding)

typedef float f32x2 __attribute__((ext_vector_type(2)));

__device__ __forceinline__ float wave_reduce_sum(float v) {
#pragma unroll
  for (int s = 32; s >= 1; s >>= 1) v += __shfl_xor(v, s, 64);
  return v;
}
__device__ __forceinline__ float wave_reduce_max(float v) {
#pragma unroll
  for (int s = 32; s >= 1; s >>= 1) v = fmaxf(v, __shfl_xor(v, s, 64));
  return v;
}
__device__ __forceinline__ float wave_reduce_min(float v) {
#pragma unroll
  for (int s = 32; s >= 1; s >>= 1) v = fminf(v, __shfl_xor(v, s, 64));
  return v;
}

__device__ __forceinline__ bool getbit(const unsigned* mb, int i) {
  return (mb[i >> 5] >> (i & 31)) & 1u;
}

// Cross-XCD potential exchange: agent-scope RELAXED atomics — sc0/sc1 flagged,
// serviced at the LLC (coherence point). No release/acquire => no buffer_wbl2 /
// buffer_inv whole-L2 maintenance. Visibility: __syncthreads drains vmcnt(0),
// and a retired sc1 store is at the LLC.
__device__ __forceinline__ void pot_st2(float* p, float lo, float hi) {
  const unsigned long long pk =
      ((unsigned long long)__float_as_uint(hi) << 32) | __float_as_uint(lo);
  __hip_atomic_store((unsigned long long*)p, pk, __ATOMIC_RELAXED,
                     __HIP_MEMORY_SCOPE_AGENT);
}
__device__ __forceinline__ void pot_ld2(const float* p, float& lo, float& hi) {
  const unsigned long long pk = __hip_atomic_load(
      (const unsigned long long*)p, __ATOMIC_RELAXED, __HIP_MEMORY_SCOPE_AGENT);
  lo = __uint_as_float((unsigned)pk);
  hi = __uint_as_float((unsigned)(pk >> 32));
}
__device__ __forceinline__ float pot_ld(const float* p) {
  return __hip_atomic_load(p, __ATOMIC_RELAXED, __HIP_MEMORY_SCOPE_AGENT);
}

// Per-batch barrier across 16 chunk-WGs (all co-resident, cooperative launch).
// bp points at a private 128 B line for this batch. Fully relaxed at agent
// scope; the trailing workgroup-scope acquire only pins compiler ordering.
// R6/R7 lesson: ONE add per WG, ONE tid0 spinner — finer granularity floods
// the LLC with contended sc-traffic and regresses badly.
__device__ __forceinline__ void batch_barrier(int* bp, int gen, int tid) {
  __syncthreads();                      // drains vmcnt(0): pot stores at LLC
  if (tid == 0) {
    __hip_atomic_fetch_add(bp, 1, __ATOMIC_RELAXED, __HIP_MEMORY_SCOPE_AGENT);
    const int target = CHUNKS * gen;
    while (__hip_atomic_load(bp, __ATOMIC_RELAXED, __HIP_MEMORY_SCOPE_AGENT) < target)
      __builtin_amdgcn_s_sleep(2);
    (void)__hip_atomic_load(bp, __ATOMIC_ACQUIRE, __HIP_MEMORY_SCOPE_WORKGROUP);
  }
  __syncthreads();
}

// Split form of the SAME protocol (used once, around the iter-0 chamfer):
// arrive after a vmcnt-draining __syncthreads; wait later (spin + barrier).
__device__ __forceinline__ void bar_arrive_only(int* bp, int tid) {
  if (tid == 0)
    __hip_atomic_fetch_add(bp, 1, __ATOMIC_RELAXED, __HIP_MEMORY_SCOPE_AGENT);
}
__device__ __forceinline__ void bar_wait_only(int* bp, int gen, int tid) {
  if (tid == 0) {
    const int target = CHUNKS * gen;
    while (__hip_atomic_load(bp, __ATOMIC_RELAXED, __HIP_MEMORY_SCOPE_AGENT) < target)
      __builtin_amdgcn_s_sleep(2);
    (void)__hip_atomic_load(bp, __ATOMIC_ACQUIRE, __HIP_MEMORY_SCOPE_WORKGROUP);
  }
  __syncthreads();
}

// ---------------------------------------------------------------------------
// Two-pass half-step (exact max) — bit-identical math to legacy sink_step.
// ---------------------------------------------------------------------------
template<bool CHAMF>
__device__ __forceinline__ void twopass(
    const float4* rl, const float4* cl, const float* Agl, const unsigned* rmb,
    float elab, int c, int wave, int lane, int tid,
    float* __restrict__ potOut, size_t base,
    float invnb, int b, float* __restrict__ cdPart, float* reds)
{
  float cdacc = 0.0f;
#pragma unroll 1
  for (int grp = 0; grp < 2; ++grp) {
    const int row0 = c * 64 + wave * 8 + grp * 4;

    float xs0[4], xs1[4], xs2[4], xw[4];
    bool rmv[4];
#pragma unroll
    for (int r = 0; r < 4; ++r) {
      const float4 xp = rl[row0 + r];
      xs0[r] = TWOK2 * xp.x; xs1[r] = TWOK2 * xp.y; xs2[r] = TWOK2 * xp.z;
      xw[r] = xp.w;
      rmv[r] = getbit(rmb, row0 + r);
    }

    float u[4][16];
#pragma unroll
    for (int j = 0; j < 16; ++j) {
      const int m = lane + j * 64;
      const float4 yp = cl[m];
      const float aj = Agl[m];
#pragma unroll
      for (int r = 0; r < 4; ++r) {
        float t = fmaf(xs0[r], yp.x, aj);
        t = fmaf(xs1[r], yp.y, t);
        t = fmaf(xs2[r], yp.z, t);
        u[r][j] = t;
      }
    }

    float gm[4];
#pragma unroll
    for (int r = 0; r < 4; ++r) {
      const float a0 = fmaxf(fmaxf(u[r][0], u[r][1]), u[r][2]);
      const float a1 = fmaxf(fmaxf(u[r][3], u[r][4]), u[r][5]);
      const float a2 = fmaxf(fmaxf(u[r][6], u[r][7]), u[r][8]);
      const float a3 = fmaxf(fmaxf(u[r][9], u[r][10]), u[r][11]);
      const float a4 = fmaxf(fmaxf(u[r][12], u[r][13]), u[r][14]);
      const float mr = fmaxf(fmaxf(fmaxf(a0, a1), a2),
                             fmaxf(fmaxf(a3, a4), u[r][15]));
      gm[r] = wave_reduce_max(mr);
    }

    float ss[4] = {0.f, 0.f, 0.f, 0.f};
#pragma unroll
    for (int j = 0; j < 16; ++j) {
#pragma unroll
      for (int r = 0; r < 4; ++r)
        ss[r] += __builtin_amdgcn_exp2f(u[r][j] - gm[r]);
    }
#pragma unroll
    for (int r = 0; r < 4; ++r) ss[r] = wave_reduce_sum(ss[r]);

    float pv[4];
#pragma unroll
    for (int r = 0; r < 4; ++r) {
      const float lse2 = gm[r] + __builtin_amdgcn_logf(ss[r]);  // log2 domain
      const float el = rmv[r] ? elab : (EPSS * NEGV);
      pv[r] = el + xw[r] - INVK2 * lse2;
    }
    if (lane == 0) {
      pot_st2(&potOut[base + row0 + 0], pv[0], pv[1]);
      pot_st2(&potOut[base + row0 + 2], pv[2], pv[3]);
      if constexpr (CHAMF) {
#pragma unroll
        for (int r = 0; r < 4; ++r)
          if (rmv[r]) cdacc += fmaxf(fmaf(-INVK2, gm[r], xw[r]), 0.0f);
      }
    }
  }

  if constexpr (CHAMF) {
    if (lane == 0) reds[wave] = cdacc;
    __syncthreads();
    if (tid == 0) {
      float s = 0.f;
#pragma unroll
      for (int w = 0; w < 8; ++w) s += reds[w];
      cdPart[(size_t)b * CHUNKS + c] = s * invnb * (1.0f / BB);
    }
  }
}

// ---------------------------------------------------------------------------
// One-pass half-step — identical IEEE ops/order to legacy sink_fast, rows
// packed in pairs as float2 => v_pk_* dual-FP32. Bit-exact per row.
// ---------------------------------------------------------------------------
__device__ __forceinline__ void onepass(
    const float4* rl, const float4* cl, const float* Agl, const unsigned* rmb,
    float elab, int row0, int lane, float* __restrict__ pot, size_t base,
    float fp[8])
{
  f32x2 xs0[4], xs1[4], xs2[4], sh2[4], acc2[4];
  bool rmv[8];
#pragma unroll
  for (int p = 0; p < 4; ++p) {
    const float4 xa = rl[row0 + 2 * p];
    const float4 xb = rl[row0 + 2 * p + 1];
    rmv[2 * p]     = getbit(rmb, row0 + 2 * p);
    rmv[2 * p + 1] = getbit(rmb, row0 + 2 * p + 1);
    xs0[p] = f32x2{TWOK2 * xa.x, TWOK2 * xb.x};
    xs1[p] = f32x2{TWOK2 * xa.y, TWOK2 * xb.y};
    xs2[p] = f32x2{TWOK2 * xa.z, TWOK2 * xb.z};
    sh2[p] = f32x2{
        rmv[2 * p]     ? (K2f * (elab + xa.w - fp[2 * p]))     : 3.0e38f,
        rmv[2 * p + 1] ? (K2f * (elab + xb.w - fp[2 * p + 1])) : 3.0e38f};
    acc2[p] = f32x2{0.f, 0.f};
  }

#pragma unroll 4
  for (int j = 0; j < 16; ++j) {
    const int m = lane + j * 64;
    const float4 q = cl[m];
    const float aj = Agl[m];
    const f32x2 qx = {q.x, q.x}, qy = {q.y, q.y}, qz = {q.z, q.z};
    const f32x2 aj2 = {aj, aj};
#pragma unroll
    for (int p = 0; p < 4; ++p) {
      f32x2 t = __builtin_elementwise_fma(xs0[p], qx, aj2);
      t = __builtin_elementwise_fma(xs1[p], qy, t);
      t = __builtin_elementwise_fma(xs2[p], qz, t);
      const f32x2 e = t - sh2[p];
      const f32x2 ex = {__builtin_amdgcn_exp2f(e.x), __builtin_amdgcn_exp2f(e.y)};
      acc2[p] += ex;
    }
  }

  float acc[8];
#pragma unroll
  for (int p = 0; p < 4; ++p) { acc[2 * p] = acc2[p].x; acc[2 * p + 1] = acc2[p].y; }
#pragma unroll
  for (int r = 0; r < 8; ++r) acc[r] = wave_reduce_sum(acc[r]);

#pragma unroll
  for (int r = 0; r < 8; ++r) {
    const float l2 = fminf(fmaxf(__builtin_amdgcn_logf(acc[r]), -120.0f), 120.0f);
    fp[r] = rmv[r] ? (fp[r] - INVK2 * l2) : (EPSS * NEGV);
  }
  if (lane == 0) {
#pragma unroll
    for (int r = 0; r < 8; r += 2)
      pot_st2(&pot[base + row0 + r], fp[r], fp[r + 1]);
  }
}

// ---------------------------------------------------------------------------
// Persistent cooperative kernel: prep + 40 Sinkhorn half-steps + both chamfer
// directions + EMD, per-batch relaxed barriers between half-steps.
// b = gid&31, c = gid>>5 (R2/R4 mapping: best measured FETCH/occupancy).
// Only change vs the verified 383 µs kernel: the gen-1 barrier is split so the
// chamfer y->x phase sits between arrive and wait (covers the spin).
// ---------------------------------------------------------------------------
__global__ __launch_bounds__(512, 4) void fused_sink(
    const float* __restrict__ xset, const int* __restrict__ xm,
    const float* __restrict__ yset, const int* __restrict__ ym,
    float* __restrict__ f, float* __restrict__ g,
    float* __restrict__ cd_part, float* __restrict__ emd_part,
    int* __restrict__ bar)
{
  const int gid = blockIdx.x;
  const int b = gid & (BB - 1), c = gid >> 5;
  const int tid = threadIdx.x, wave = tid >> 6, lane = tid & 63;
  const size_t base = (size_t)b * NN;
  int* bp = bar + b * BARSTRIDE;

  __shared__ float4 xl[NN];            // 16 KB  points x (x,y,z,|p|^2)
  __shared__ float4 yl[NN];            // 16 KB  points y
  __shared__ float Ag[NN];             //  4 KB  prefolded column terms
  __shared__ float gvs[NN];            //  4 KB  staging (EMD g / chamfer w)
  __shared__ unsigned xmb[NN / 32], ymb[NN / 32];
  __shared__ float cred[16];
  __shared__ float reds[8];
  __shared__ float sscal[4];           // elax, elay, invx, invy

  // ---- stage points + masks once ----
  float cntx = 0.f, cnty = 0.f;
  for (int i = tid; i < NN; i += 512) {
    const size_t ix = (base + (size_t)i) * 3;
    const float x0 = xset[ix], x1 = xset[ix + 1], x2 = xset[ix + 2];
    const float y0 = yset[ix], y1 = yset[ix + 1], y2 = yset[ix + 2];
    xl[i] = make_float4(x0, x1, x2, x0 * x0 + x1 * x1 + x2 * x2);
    yl[i] = make_float4(y0, y1, y2, y0 * y0 + y1 * y1 + y2 * y2);
    const int mxv = xm[base + i], myv = ym[base + i];
    cntx += mxv ? 1.0f : 0.0f;
    cnty += myv ? 1.0f : 0.0f;
    const unsigned long long bx = __ballot(mxv != 0);
    const unsigned long long by = __ballot(myv != 0);
    if (lane == 0) {
      const int w0 = i >> 5;           // i is 64-aligned for lane 0
      xmb[w0] = (unsigned)bx; xmb[w0 + 1] = (unsigned)(bx >> 32);
      ymb[w0] = (unsigned)by; ymb[w0 + 1] = (unsigned)(by >> 32);
    }
  }
  cntx = wave_reduce_sum(cntx);
  cnty = wave_reduce_sum(cnty);
  if (lane == 0) { cred[wave] = cntx; cred[8 + wave] = cnty; }
  __syncthreads();
  if (tid == 0) {
    float a = 0.f, cc = 0.f;
#pragma unroll
    for (int i = 0; i < 8; ++i) { a += cred[i]; cc += cred[8 + i]; }
    sscal[0] = -EPSS * logf(a);        // elax
    sscal[1] = -EPSS * logf(cc);       // elay
    sscal[2] = 1.0f / a;               // invx
    sscal[3] = 1.0f / cc;              // invy
  }
  __syncthreads();
  const float elax = sscal[0], elay = sscal[1], invx = sscal[2], invy = sscal[3];
  int gen = 0;

  // ---- iter 0: f-step (two-pass, g = 0) + fused chamfer x->y ----
  for (int i = tid; i < NN; i += 512)
    Ag[i] = getbit(ymb, i) ? (-K2f * yl[i].w) : -1e30f;
  __syncthreads();
  twopass<true>(xl, yl, Ag, xmb, elax, c, wave, lane, tid, f, base,
                invx, b, cd_part, reds);
  // twopass<true>'s trailing __syncthreads drained vmcnt => f stores at LLC.
  bar_arrive_only(bp, tid);            // arrive gen 1 BEFORE chamfer

  // ---- chamfer y->x (independent of sinkhorn state; covers the gen-1 wait) ----
  for (int i = tid; i < NN; i += 512)
    gvs[i] = getbit(xmb, i) ? xl[i].w : BIGC;   // mask-folded |x|^2
  __syncthreads();
  {
    float acc = 0.0f;
#pragma unroll 1
    for (int rr = 0; rr < 8; ++rr) {
      const int row = c * 64 + wave * 8 + rr;
      const float4 yp = yl[row];
      const float ys0 = -2.f * yp.x, ys1 = -2.f * yp.y, ys2 = -2.f * yp.z;
      float dmin = BIGC;
#pragma unroll
      for (int j = 0; j < 16; ++j) {
        const int m = lane + j * 64;
        const float4 xq = xl[m];
        float d = fmaf(ys0, xq.x, gvs[m]);
        d = fmaf(ys1, xq.y, d);
        d = fmaf(ys2, xq.z, d);
        dmin = fminf(dmin, d);
      }
      dmin = wave_reduce_min(dmin);
      if (lane == 0 && getbit(ymb, row)) acc += fmaxf(yp.w + dmin, 0.0f);
    }
    __syncthreads();                   // protect reds reuse
    if (lane == 0) reds[wave] = acc;
    __syncthreads();
    if (tid == 0) {
      float s = 0.f;
#pragma unroll
      for (int w = 0; w < 8; ++w) s += reds[w];
      cd_part[BB * CHUNKS + (size_t)b * CHUNKS + c] = s * invy * (1.0f / BB);
    }
  }

  bar_wait_only(bp, 1, tid);           // f published (usually free now)
  gen = 1;

  // ---- iter 0: g-step (two-pass, pot_in = f) ----
  {
    const int i2 = tid << 1;
    float f0, f1;
    pot_ld2(&f[base + i2], f0, f1);
    Ag[i2]     = getbit(xmb, i2)     ? fmaf(K2f, f0, -K2f * xl[i2].w)     : -1e30f;
    Ag[i2 + 1] = getbit(xmb, i2 + 1) ? fmaf(K2f, f1, -K2f * xl[i2 + 1].w) : -1e30f;
  }
  __syncthreads();
  twopass<false>(yl, xl, Ag, ymb, elay, c, wave, lane, tid, g, base,
                 0.f, b, nullptr, reds);

  // ---- pull own-row potentials into registers (wave-uniform) ----
  float myf[8], myg[8];
  __syncthreads();                     // drain lane-0 g stores (vmcnt)
  {
    const int row0w = c * 64 + wave * 8;
#pragma unroll
    for (int r = 0; r < 8; r += 2) {
      pot_ld2(&f[base + row0w + r], myf[r], myf[r + 1]);
      pot_ld2(&g[base + row0w + r], myg[r], myg[r + 1]);
    }
  }

  batch_barrier(bp, ++gen, tid);       // g published (gen 2)

  // ---- iterations 1..19: one-pass half-steps ----
  const int row0w = c * 64 + wave * 8;
  for (int it = 1; it < SINK_ITERS; ++it) {
    {
      const int i2 = tid << 1;
      float g0, g1;
      pot_ld2(&g[base + i2], g0, g1);
      Ag[i2]     = getbit(ymb, i2)     ? fmaf(K2f, g0, -K2f * yl[i2].w)     : -1e30f;
      Ag[i2 + 1] = getbit(ymb, i2 + 1) ? fmaf(K2f, g1, -K2f * yl[i2 + 1].w) : -1e30f;
    }
    __syncthreads();
    onepass(xl, yl, Ag, xmb, elax, row0w, lane, f, base, myf);
    batch_barrier(bp, ++gen, tid);

    {
      const int i2 = tid << 1;
      float f0, f1;
      pot_ld2(&f[base + i2], f0, f1);
      Ag[i2]     = getbit(xmb, i2)     ? fmaf(K2f, f0, -K2f * xl[i2].w)     : -1e30f;
      Ag[i2 + 1] = getbit(xmb, i2 + 1) ? fmaf(K2f, f1, -K2f * xl[i2 + 1].w) : -1e30f;
    }
    __syncthreads();
    onepass(yl, xl, Ag, ymb, elay, row0w, lane, g, base, myg);
    batch_barrier(bp, ++gen, tid);
  }

  // ---- EMD plan evaluation ----
  {
    const int i2 = tid << 1;
    float g0, g1;
    pot_ld2(&g[base + i2], g0, g1);
    gvs[i2] = g0; gvs[i2 + 1] = g1;
    Ag[i2]     = getbit(ymb, i2)     ? fmaf(K2f, g0, -K2f * yl[i2].w)     : -1e30f;
    Ag[i2 + 1] = getbit(ymb, i2 + 1) ? fmaf(K2f, g1, -K2f * yl[i2 + 1].w) : -1e30f;
  }
  __syncthreads();
  {
    float acc = 0.0f;
#pragma unroll 1
    for (int rr = 0; rr < 8; ++rr) {
      const int row = c * 64 + wave * 8 + rr;
      const float4 xp = xl[row];
      const float fv = pot_ld(&f[base + row]);
      const float rc = fmaf(K2f, fv, -K2f * xp.w);
      const float xs0 = TWOK2 * xp.x, xs1 = TWOK2 * xp.y, xs2 = TWOK2 * xp.z;
      const bool rv = getbit(xmb, row);
#pragma unroll
      for (int j = 0; j < 16; ++j) {
        const int m = lane + j * 64;
        const float4 yp = yl[m];
        const float a = rv ? (Ag[m] + rc) : -1e30f;
        float t = fmaf(xs0, yp.x, a);
        t = fmaf(xs1, yp.y, t);
        t = fmaf(xs2, yp.z, t);
        float C = fmaf(t, -INVK2, fv + gvs[m]);
        C = fmaxf(C, 0.0f);
        acc = fmaf(__builtin_amdgcn_exp2f(t), C, acc);
      }
    }
    acc = wave_reduce_sum(acc);
    __syncthreads();
    if (lane == 0) reds[wave] = acc;
    __syncthreads();
    if (tid == 0) {
      float s = 0.f;
#pragma unroll
      for (int w = 0; w < 8; ++w) s += reds[w];
      emd_part[(size_t)b * CHUNKS + c] = s * (1.0f / BB);
    }
  }
}

// ===========================================================================
// Legacy multi-kernel path (fallback if cooperative launch is unavailable).
// ===========================================================================
__global__ __launch_bounds__(1024) void prep_kernel(
    const float* __restrict__ xset, const int* __restrict__ xm,
    const float* __restrict__ yset, const int* __restrict__ ym,
    float4* __restrict__ xpack, float4* __restrict__ ypack,
    float* __restrict__ elax, float* __restrict__ elay,
    float* __restrict__ invx, float* __restrict__ invy)
{
  const int b = blockIdx.x;
  const int n = threadIdx.x;
  const size_t idx = (size_t)b * NN + n;

  const float x0 = xset[idx * 3 + 0], x1 = xset[idx * 3 + 1], x2 = xset[idx * 3 + 2];
  const float y0 = yset[idx * 3 + 0], y1 = yset[idx * 3 + 1], y2 = yset[idx * 3 + 2];
  xpack[idx] = make_float4(x0, x1, x2, x0 * x0 + x1 * x1 + x2 * x2);
  ypack[idx] = make_float4(y0, y1, y2, y0 * y0 + y1 * y1 + y2 * y2);

  float cx = wave_reduce_sum(xm[idx] ? 1.0f : 0.0f);
  float cy = wave_reduce_sum(ym[idx] ? 1.0f : 0.0f);

  __shared__ float sx[16], sy[16];
  const int wave = n >> 6, lane = n & 63;
  if (lane == 0) { sx[wave] = cx; sy[wave] = cy; }
  __syncthreads();
  if (n == 0) {
    float a = 0.0f, c = 0.0f;
#pragma unroll
    for (int i = 0; i < 16; ++i) { a += sx[i]; c += sy[i]; }
    elax[b] = -EPSS * logf(a);
    elay[b] = -EPSS * logf(c);
    invx[b] = 1.0f / a;
    invy[b] = 1.0f / c;
  }
}

template<bool FIRST, bool CHAMF>
__global__ __launch_bounds__(512) void sink_step(
    const float4* __restrict__ rowpk, const float4* __restrict__ redpk,
    const int* __restrict__ rowmask, const int* __restrict__ redmask,
    const float* __restrict__ pot_in, float* __restrict__ pot_out,
    const float* __restrict__ ela,
    const float* __restrict__ invn,
    float* __restrict__ cd_part)
{
  const int b = blockIdx.y, chunk = blockIdx.x, tid = threadIdx.x;
  const int wave = tid >> 6, lane = tid & 63;
  const size_t base = (size_t)b * NN;

  __shared__ float4 ypk[NN];
  __shared__ float Aj[NN];
  __shared__ float reds[8];

  for (int i = tid; i < NN; i += 512) {
    const float4 yp = redpk[base + i];
    ypk[i] = yp;
    float a;
    if constexpr (FIRST)
      a = redmask[base + i] ? (-K2f * yp.w) : -1e30f;
    else
      a = redmask[base + i] ? fmaf(K2f, pot_in[base + i], -K2f * yp.w) : -1e30f;
    Aj[i] = a;
  }
  __syncthreads();

  const float elab = ela[b];
  float cdacc = 0.0f;

#pragma unroll 1
  for (int grp = 0; grp < 2; ++grp) {
    const int row0 = chunk * 64 + wave * 8 + grp * 4;

    float xs0[4], xs1[4], xs2[4], xw[4];
    int rmv[4];
#pragma unroll
    for (int r = 0; r < 4; ++r) {
      const float4 xp = rowpk[base + row0 + r];
      xs0[r] = TWOK2 * xp.x; xs1[r] = TWOK2 * xp.y; xs2[r] = TWOK2 * xp.z;
      xw[r] = xp.w;
      rmv[r] = rowmask[base + row0 + r];
    }

    float u[4][16];
#pragma unroll
    for (int j = 0; j < 16; ++j) {
      const int m = lane + j * 64;
      const float4 yp = ypk[m];
      const float aj = Aj[m];
#pragma unroll
      for (int r = 0; r < 4; ++r) {
        float t = fmaf(xs0[r], yp.x, aj);
        t = fmaf(xs1[r], yp.y, t);
        t = fmaf(xs2[r], yp.z, t);
        u[r][j] = t;
      }
    }

    float gm[4];
#pragma unroll
    for (int r = 0; r < 4; ++r) {
      const float a0 = fmaxf(fmaxf(u[r][0], u[r][1]), u[r][2]);
      const float a1 = fmaxf(fmaxf(u[r][3], u[r][4]), u[r][5]);
      const float a2 = fmaxf(fmaxf(u[r][6], u[r][7]), u[r][8]);
      const float a3 = fmaxf(fmaxf(u[r][9], u[r][10]), u[r][11]);
      const float a4 = fmaxf(fmaxf(u[r][12], u[r][13]), u[r][14]);
      const float mr = fmaxf(fmaxf(fmaxf(a0, a1), a2),
                             fmaxf(fmaxf(a3, a4), u[r][15]));
      gm[r] = wave_reduce_max(mr);
    }

    float ss[4] = {0.f, 0.f, 0.f, 0.f};
#pragma unroll
    for (int j = 0; j < 16; ++j) {
#pragma unroll
      for (int r = 0; r < 4; ++r)
        ss[r] += __builtin_amdgcn_exp2f(u[r][j] - gm[r]);
    }
#pragma unroll
    for (int r = 0; r < 4; ++r) ss[r] = wave_reduce_sum(ss[r]);

    if (lane == 0) {
#pragma unroll
      for (int r = 0; r < 4; ++r) {
        const float lse2 = gm[r] + __builtin_amdgcn_logf(ss[r]);
        const float el = rmv[r] ? elab : (EPSS * NEGV);
        pot_out[base + row0 + r] = el + xw[r] - INVK2 * lse2;
        if constexpr (CHAMF) {
          if (rmv[r])
            cdacc += fmaxf(fmaf(-INVK2, gm[r], xw[r]), 0.0f);
        }
      }
    }
  }

  if constexpr (CHAMF) {
    if (lane == 0) reds[wave] = cdacc;
    __syncthreads();
    if (tid == 0) {
      float s = 0.f;
#pragma unroll
      for (int w = 0; w < 8; ++w) s += reds[w];
      cd_part[(size_t)b * CHUNKS + chunk] = s * invn[b] * (1.0f / BB);
    }
  }
}

__global__ __launch_bounds__(512) void sink_fast(
    const float4* __restrict__ rowpk, const float4* __restrict__ redpk,
    const int* __restrict__ rowmask, const int* __restrict__ redmask,
    const float* __restrict__ pot_in, float* __restrict__ fpot,
    const float* __restrict__ ela)
{
  const int b = blockIdx.y, chunk = blockIdx.x, tid = threadIdx.x;
  const int wave = tid >> 6, lane = tid & 63;
  const size_t base = (size_t)b * NN;

  __shared__ float4 colq[NN];

  for (int i = tid; i < NN; i += 512) {
    const float4 yp = redpk[base + i];
    const float aj = redmask[base + i]
        ? fmaf(K2f, pot_in[base + i], -K2f * yp.w) : -1e30f;
    colq[i] = make_float4(yp.x, yp.y, yp.z, aj);
  }
  __syncthreads();

  const float elab = ela[b];
  const int row0 = chunk * 64 + wave * 8;

  float xs0[8], xs1[8], xs2[8], sh[8], acc[8], fp[8];
  int rmv[8];
#pragma unroll
  for (int r = 0; r < 8; ++r) {
    const float4 xp = rowpk[base + row0 + r];
    rmv[r] = rowmask[base + row0 + r];
    fp[r] = fpot[base + row0 + r];
    xs0[r] = TWOK2 * xp.x; xs1[r] = TWOK2 * xp.y; xs2[r] = TWOK2 * xp.z;
    sh[r] = rmv[r] ? (K2f * (elab + xp.w - fp[r])) : 3.0e38f;
    acc[r] = 0.0f;
  }

#pragma unroll 4
  for (int j = 0; j < 16; ++j) {
    const float4 q = colq[lane + j * 64];
#pragma unroll
    for (int r = 0; r < 8; ++r) {
      float t = fmaf(xs0[r], q.x, q.w);
      t = fmaf(xs1[r], q.y, t);
      t = fmaf(xs2[r], q.z, t);
      acc[r] += __builtin_amdgcn_exp2f(t - sh[r]);
    }
  }

#pragma unroll
  for (int r = 0; r < 8; ++r) acc[r] = wave_reduce_sum(acc[r]);

  if (lane == 0) {
#pragma unroll
    for (int r = 0; r < 8; ++r) {
      const float l2 = fminf(fmaxf(__builtin_amdgcn_logf(acc[r]), -120.0f), 120.0f);
      fpot[base + row0 + r] = rmv[r] ? (fp[r] - INVK2 * l2) : (EPSS * NEGV);
    }
  }
}

__global__ __launch_bounds__(512) void chamfer_dir(
    const float4* __restrict__ rowpk, const float4* __restrict__ redpk,
    const int* __restrict__ rowmask, const int* __restrict__ redmask,
    const float* __restrict__ invn, float* __restrict__ part)
{
  const int b = blockIdx.y, chunk = blockIdx.x, tid = threadIdx.x;
  const int wave = tid >> 6, lane = tid & 63;
  const size_t base = (size_t)b * NN;

  __shared__ float4 xw4[NN];
  for (int i = tid; i < NN; i += 512) {
    float4 xp = redpk[base + i];
    xp.w = redmask[base + i] ? xp.w : BIGC;
    xw4[i] = xp;
  }
  __syncthreads();

  float acc = 0.0f;
#pragma unroll 1
  for (int rr = 0; rr < 8; ++rr) {
    const int row = chunk * 64 + wave * 8 + rr;
    const float4 yp = rowpk[base + row];
    const float ys0 = -2.f * yp.x, ys1 = -2.f * yp.y, ys2 = -2.f * yp.z;
    float dmin = BIGC;
#pragma unroll
    for (int j = 0; j < 16; ++j) {
      const float4 xq = xw4[lane + j * 64];
      float d = fmaf(ys0, xq.x, xq.w);
      d = fmaf(ys1, xq.y, d);
      d = fmaf(ys2, xq.z, d);
      dmin = fminf(dmin, d);
    }
    dmin = wave_reduce_min(dmin);
    if (lane == 0 && rowmask[base + row]) acc += fmaxf(yp.w + dmin, 0.0f);
  }

  __shared__ float reds[8];
  if (lane == 0) reds[wave] = acc;
  __syncthreads();
  if (tid == 0) {
    float s = 0.f;
#pragma unroll
    for (int w = 0; w < 8; ++w) s += reds[w];
    part[(size_t)b * CHUNKS + chunk] = s * invn[b] * (1.0f / BB);
  }
}

__global__ __launch_bounds__(512) void emd_kernel(
    const float4* __restrict__ rowpk, const float4* __restrict__ redpk,
    const int* __restrict__ rowmask, const int* __restrict__ redmask,
    const float* __restrict__ frow, const float* __restrict__ gred,
    float* __restrict__ part)
{
  const int b = blockIdx.y, chunk = blockIdx.x, tid = threadIdx.x;
  const int wave = tid >> 6, lane = tid & 63;
  const size_t base = (size_t)b * NN;

  __shared__ float4 ypk[NN];
  __shared__ float Ag[NN];
  __shared__ float gv[NN];
  for (int i = tid; i < NN; i += 512) {
    const float4 yp = redpk[base + i];
    ypk[i] = yp;
    const float gg = gred[base + i];
    gv[i] = gg;
    Ag[i] = redmask[base + i] ? fmaf(K2f, gg, -K2f * yp.w) : -1e30f;
  }
  __syncthreads();

  float acc = 0.0f;
#pragma unroll 1
  for (int rr = 0; rr < 8; ++rr) {
    const int row = chunk * 64 + wave * 8 + rr;
    const float4 xp = rowpk[base + row];
    const float fv = frow[base + row];
    const float rc = fmaf(K2f, fv, -K2f * xp.w);
    const float xs0 = TWOK2 * xp.x, xs1 = TWOK2 * xp.y, xs2 = TWOK2 * xp.z;
    const bool rv = rowmask[base + row] != 0;
#pragma unroll
    for (int j = 0; j < 16; ++j) {
      const int m = lane + j * 64;
      const float4 yp = ypk[m];
      const float a = rv ? (Ag[m] + rc) : -1e30f;
      float t = fmaf(xs0, yp.x, a);
      t = fmaf(xs1, yp.y, t);
      t = fmaf(xs2, yp.z, t);
      float C = fmaf(t, -INVK2, fv + gv[m]);
      C = fmaxf(C, 0.0f);
      acc = fmaf(__builtin_amdgcn_exp2f(t), C, acc);
    }
  }

  acc = wave_reduce_sum(acc);
  __shared__ float reds[8];
  if (lane == 0) reds[wave] = acc;
  __syncthreads();
  if (tid == 0) {
    float s = 0.f;
#pragma unroll
    for (int w = 0; w < 8; ++w) s += reds[w];
    part[(size_t)b * CHUNKS + chunk] = s * (1.0f / BB);
  }
}

__global__ __launch_bounds__(256) void final_kernel(
    const float* __restrict__ cd_part, const float* __restrict__ emd_part,
    const float* __restrict__ kls, float* __restrict__ out)
{
  const int tid = threadIdx.x, wave = tid >> 6, lane = tid & 63;
  __shared__ float sh[12];
  float s1 = 0.f, s2 = 0.f, s3 = 0.f;
  for (int i = tid; i < 2 * BB * CHUNKS; i += 256) s1 += cd_part[i];
  for (int i = tid; i < BB * CHUNKS; i += 256) s2 += emd_part[i];
  for (int i = tid; i < BB * 5; i += 256) s3 += kls[i];
  s1 = wave_reduce_sum(s1); s2 = wave_reduce_sum(s2); s3 = wave_reduce_sum(s3);
  if (lane == 0) { sh[wave] = s1; sh[4 + wave] = s2; sh[8 + wave] = s3; }
  __syncthreads();
  if (tid == 0) {
    const float cd = sh[0] + sh[1] + sh[2] + sh[3];
    const float emd = sh[4] + sh[5] + sh[6] + sh[7];
    const float kl = (sh[8] + sh[9] + sh[10] + sh[11]) / (float)BB;
    out[0] = 0.01f * kl + (cd + emd);
    out[1] = kl;
    out[2] = cd + emd;
  }
  if (tid < 5) {
    float cs = 0.f;
    for (int b2 = 0; b2 < BB; ++b2) cs += kls[b2 * 5 + tid];
    const float zs[5] = {2.f, 4.f, 8.f, 16.f, 32.f};
    out[3 + tid] = (cs / (float)BB) / (zs[tid] * 16.f);
  }
}

// ---------------------------------------------------------------------------
extern "C" void kernel_launch(void* const* d_in, const int* in_sizes, int n_in,
                              void* d_out, int out_size, void* d_ws, size_t ws_size,
                              hipStream_t stream)
{
  const float* xset = (const float*)d_in[0];
  const int*   xm   = (const int*)d_in[1];
  const float* yset = (const float*)d_in[2];
  const int*   ym   = (const int*)d_in[3];
  const float* kls  = (const float*)d_in[4];

  float* ws = (float*)d_ws;
  float*  f    = ws;                         // 32768
  float*  g    = f + BB * NN;                // 32768
  float*  cd   = g + BB * NN;                // 2*BB*CHUNKS = 1024
  float*  emdp = cd + 2 * BB * CHUNKS;       // BB*CHUNKS = 512
  float*  elax = emdp + BB * CHUNKS;         // BB (legacy path)
  float*  elay = elax + BB;
  float*  invx = elay + BB;
  float*  invy = invx + BB;
  int*    bar  = (int*)(invy + BB);          // BB*BARSTRIDE ints (padded)
  float4* xp4  = (float4*)(ws + 68256);      // legacy path, after bar region
  float4* yp4  = xp4 + BB * NN;

  // barrier counters must start at 0 each launch
  hipMemsetAsync(bar, 0, BB * BARSTRIDE * sizeof(int), stream);

  void* args[] = {(void*)&xset, (void*)&xm, (void*)&yset, (void*)&ym,
                  (void*)&f, (void*)&g, (void*)&cd, (void*)&emdp, (void*)&bar};
  hipError_t cerr = hipLaunchCooperativeKernel(
      reinterpret_cast<void*>(fused_sink), dim3(NBLK), dim3(512), args, 0, stream);

  if (cerr != hipSuccess) {
    // fallback: verified legacy multi-kernel path
    prep_kernel<<<dim3(BB), 1024, 0, stream>>>(xset, xm, yset, ym,
                                               xp4, yp4, elax, elay, invx, invy);
    const dim3 sg(CHUNKS, BB);
    sink_step<true, true><<<sg, 512, 0, stream>>>(xp4, yp4, xm, ym, nullptr, f,
                                                  elax, invx, cd);
    chamfer_dir<<<sg, 512, 0, stream>>>(yp4, xp4, ym, xm, invy, cd + BB * CHUNKS);
    sink_step<false, false><<<sg, 512, 0, stream>>>(yp4, xp4, ym, xm, f, g,
                                                    elay, nullptr, nullptr);
    for (int it = 1; it < SINK_ITERS; ++it) {
      sink_fast<<<sg, 512, 0, stream>>>(xp4, yp4, xm, ym, g, f, elax);
      sink_fast<<<sg, 512, 0, stream>>>(yp4, xp4, ym, xm, f, g, elay);
    }
    emd_kernel<<<sg, 512, 0, stream>>>(xp4, yp4, xm, ym, f, g, emdp);
  }

  final_kernel<<<1, 256, 0, stream>>>(cd, emdp, kls, (float*)d_out);
}